// Round 13
// baseline (873.498 us; speedup 1.0000x reference)
//
#include <hip/hip_runtime.h>

typedef __bf16 bf16;
using bf16x8 = __attribute__((ext_vector_type(8))) __bf16;
using bf16x4 = __attribute__((ext_vector_type(4))) __bf16;
using f32x4  = __attribute__((ext_vector_type(4))) float;

#define DEV __device__ __forceinline__
#define SCHED_FENCE() __builtin_amdgcn_sched_barrier(0)

DEV float gelu_f(float x){ return 0.5f*x*(1.0f+erff(x*0.7071067811865475f)); }
DEV float sigm_f(float x){ return 1.0f/(1.0f+expf(-x)); }

DEV void gload16(const bf16* g, bf16* l){
    __builtin_amdgcn_global_load_lds(
        (const __attribute__((address_space(1))) void*)g,
        (__attribute__((address_space(3))) void*)l, 16, 0, 0);
}

enum { EPI_ADJ=0, EPI_BF16=1, EPI_GELU_BIAS=2, EPI_XUPD=3, EPI_BIAS_F32=4, EPI_F32=5, EPI_XUPDB=6 };

// ---------------------------------------------------------------------------
// r5-proven GEMM: BK=64, 2 LDS buffers, counted vmcnt, both-sides swizzle.
// TRIU=1: symmetric output — compute only upper-triangle tiles (bx>=by);
// grid = nbm*(nbm+1)/2 blocks (mirror kernel fills the rest).
// ---------------------------------------------------------------------------
template<int BM,int BN,int WM,int WN,int MINW,int TRIU,int EPI>
__global__ __launch_bounds__(WM*WN*64, MINW)
void gemm_p(const bf16* __restrict__ A, const bf16* __restrict__ B,
            int M, int N, int K, void* __restrict__ Cout, int ldc,
            const float* __restrict__ bias, const float* __restrict__ scal, int sidx,
            float* __restrict__ xu0, float* __restrict__ xu1, bf16* __restrict__ xbp)
{
    constexpr int THREADS = WM*WN*64;
    constexpr int MR = BM/WM/16, NR = BN/WN/16;
    constexpr int ATILE = BM*64, BTILE = BN*64;
    constexpr int RR = THREADS/8;
    constexpr int VM = (BM+BN)/RR;
    __shared__ bf16 sm[2*(ATILE+BTILE)];

    const int nbm = M/BM, nbn = N/BN;
    const int nwg = TRIU ? (nbm*(nbm+1))/2 : nbm*nbn;
    int wg = blockIdx.x;
    wg = (wg&7)*(nwg>>3) + (wg>>3);
    int by, bx;
    if constexpr (TRIU){
        int i = wg, r = 0;
        while (i >= nbm - r){ i -= nbm - r; ++r; }
        by = r; bx = r + i;                      // bx >= by
    } else {
        by = wg % nbm; bx = wg / nbm;
    }
    const int tid = threadIdx.x, lane = tid&63, wid = tid>>6;
    const int wm = wid / WN, wn = wid % WN;
    const int fr = lane&15, fq = lane>>4;

    const bf16* Ab = A + (long)(by*BM + (tid>>3))*K + (((tid&7) ^ ((tid>>3)&7))<<3);
    const bf16* Bb = B + (long)(bx*BN + (tid>>3))*K + (((tid&7) ^ ((tid>>3)&7))<<3);

    auto STAGE = [&](int tt, int cb){
        bf16* d = sm + cb*(ATILE+BTILE) + wid*512;
        const long ko = (long)tt*64;
#pragma unroll
        for (int g=0; g<BM/RR; ++g)
            gload16(Ab + (long)g*RR*K + ko, d + g*RR*64);
#pragma unroll
        for (int g=0; g<BN/RR; ++g)
            gload16(Bb + (long)g*RR*K + ko, d + ATILE + g*RR*64);
    };

    f32x4 acc[MR][NR] = {};
    const int nt = K >> 6;

    STAGE(0,0);
    STAGE(1,1);

    for (int t=0; t<nt; ++t){
        const bf16* bufA = sm + (t&1)*(ATILE+BTILE);
        const bf16* bufB = bufA + ATILE;
        if (t+1<nt){
            if constexpr (VM==6)      asm volatile("s_waitcnt vmcnt(6)" ::: "memory");
            else if constexpr (VM==8) asm volatile("s_waitcnt vmcnt(8)" ::: "memory");
            else                      asm volatile("s_waitcnt vmcnt(0)" ::: "memory");
        } else {
            asm volatile("s_waitcnt vmcnt(0)" ::: "memory");
        }
        __builtin_amdgcn_s_barrier();
        __builtin_amdgcn_sched_barrier(0);
#pragma unroll
        for (int ks=0; ks<2; ++ks){
            bf16x8 af[MR], bv[NR];
            const int ch = (((ks*4+fq) ^ (fr&7))<<3);
#pragma unroll
            for (int j=0;j<MR;++j)
                af[j] = *(const bf16x8*)&bufA[(wm*(MR*16) + j*16 + fr)*64 + ch];
#pragma unroll
            for (int j=0;j<NR;++j)
                bv[j] = *(const bf16x8*)&bufB[(wn*(NR*16) + j*16 + fr)*64 + ch];
            __builtin_amdgcn_s_setprio(1);
#pragma unroll
            for (int mi=0;mi<MR;++mi)
#pragma unroll
            for (int ni=0;ni<NR;++ni)
                acc[mi][ni] = __builtin_amdgcn_mfma_f32_16x16x32_bf16(
                    af[mi], bv[ni], acc[mi][ni], 0,0,0);
            __builtin_amdgcn_s_setprio(0);
        }
        asm volatile("s_waitcnt lgkmcnt(0)" ::: "memory");
        __builtin_amdgcn_s_barrier();
        if (t+2<nt) STAGE(t+2, t&1);
    }

    float thr = 0.f;
    if constexpr (EPI==EPI_ADJ) thr = scal[sidx];

#pragma unroll
    for (int mi=0;mi<MR;++mi){
#pragma unroll
        for (int ni=0;ni<NR;++ni){
            const int col = bx*BN + wn*(NR*16) + ni*16 + fr;
#pragma unroll
            for (int r=0;r<4;++r){
                const int row = by*BM + wm*(MR*16) + mi*16 + fq*4 + r;
                const float v = acc[mi][ni][r];
                const long ci = (long)row*ldc + col;
                if constexpr (EPI==EPI_ADJ)       ((bf16*)Cout)[ci] = (bf16)sigm_f(10.f*(v - thr));
                else if constexpr (EPI==EPI_BF16) ((bf16*)Cout)[ci] = (bf16)v;
                else if constexpr (EPI==EPI_GELU_BIAS) ((bf16*)Cout)[ci] = (bf16)gelu_f(v + bias[col]);
                else if constexpr (EPI==EPI_BIAS_F32)  ((float*)Cout)[ci] = v + bias[col];
                else if constexpr (EPI==EPI_F32)       ((float*)Cout)[ci] = v;
                else if constexpr (EPI==EPI_XUPD){
                    const float u = 0.2f*(v + bias[col]);
                    xu0[ci] += u;  xu1[ci] += u;
                }
                else if constexpr (EPI==EPI_XUPDB){
                    const float u = 0.2f*(v + bias[col]);
                    const float n0 = xu0[ci] + u, n1 = xu1[ci] + u;
                    xu0[ci] = n0;  xu1[ci] = n1;
                    xbp[ci] = (bf16)n0;
                    xbp[ci + (long)2048*1024] = (bf16)n1;
                }
            }
        }
    }
}

// ---------------------------------------------------------------------------
// mirror lower triangle of symmetric 2048x2048 bf16 adj from upper tiles.
// 120 lower 128-tiles x 16 32x32 subtiles = 1920 blocks.
// ---------------------------------------------------------------------------
__global__ void mirror_kernel(bf16* __restrict__ adj)
{
    const int b = blockIdx.x;
    int t128 = b >> 4, sub = b & 15;
    int i = t128, BY = 1;
    while (i >= BY){ i -= BY; ++BY; }            // BY in [1,15], BX < BY
    const int BX = i;
    const int r0 = BY*128 + (sub>>2)*32, c0 = BX*128 + (sub&3)*32;
    __shared__ bf16 tile[32][33];
    const int tx = threadIdx.x & 31, ty = threadIdx.x >> 5;
#pragma unroll
    for (int k=0;k<32;k+=8)
        tile[ty+k][tx] = adj[(long)(c0+ty+k)*2048 + r0+tx];   // upper source
    __syncthreads();
#pragma unroll
    for (int k=0;k<32;k+=8)
        adj[(long)(r0+ty+k)*2048 + c0+tx] = tile[tx][ty+k];   // lower dest
}

// ---------------------------------------------------------------------------
// 8-phase head GEMM (r11/r12 verified): 256x256, quadrant phases, phase-
// aligned A staging units, vmcnt(6) steady state, full fencing, N-inner.
// ---------------------------------------------------------------------------
template<int EPI>
__global__ __launch_bounds__(512, 2)
void gemm8(const bf16* __restrict__ A, const bf16* __restrict__ B,
           int M, int N, int K, void* __restrict__ Cout, int ldc,
           const float* __restrict__ bias)
{
    __shared__ bf16 sm[65536];
    const int nbm = M>>8, nbn = N>>8;
    const int nwg = nbm*nbn;
    int wg = blockIdx.x;
    wg = (wg&7)*(nwg>>3) + (wg>>3);
    const int bx = wg % nbn, by = wg / nbn;
    const int tid = threadIdx.x, lane = tid&63, wid = tid>>6;
    const int wm = wid>>2, wn = wid&3;
    const int fr = lane&15, fq = lane>>4;

    const bf16* Ag = A + (long)(by*256 + (tid>>3))*K + (((tid&7) ^ ((tid>>3)&7))<<3);
    const bf16* Bg = B + (long)(bx*256 + (tid>>3))*K + (((tid&7) ^ ((tid>>3)&7))<<3);

    auto SA = [&](int tt, int h){
        bf16* d = sm + (tt&1)*32768 + wid*512;
        const long ko = (long)tt*64;
        gload16(Ag + (long)(h*64)*K + ko,       d + h*4096);
        gload16(Ag + (long)(128+h*64)*K + ko,   d + 8192 + h*4096);
    };
    auto SB = [&](int tt, int h){
        bf16* d = sm + (tt&1)*32768 + 16384 + wid*512;
        const long ko = (long)tt*64;
#pragma unroll
        for (int g=0; g<2; ++g)
            gload16(Bg + (long)(h*2+g)*64*K + ko, d + (h*2+g)*4096);
    };

    f32x4 acc[8][4] = {};
    bf16x8 aCur[8], b0[4], b1[4];
    const int nt = K >> 6;

    SA(0,0); SB(0,0); SA(0,1); SB(0,1);
    SA(1,0); SB(1,0); SA(1,1);
    SCHED_FENCE();

    for (int t=0; t<nt; ++t){
        const bf16* bufA = sm + (t&1)*32768;
        const bf16* bufB = bufA + 16384;

        auto LDA = [&](int mh){
#pragma unroll
            for (int ks=0;ks<2;++ks){
                const int ch = (((ks*4+fq) ^ (fr&7))<<3);
#pragma unroll
                for (int j=0;j<4;++j)
                    aCur[ks*4+j] = *(const bf16x8*)&bufA[(wm*128 + mh*64 + j*16 + fr)*64 + ch];
            }
        };
        auto LDB = [&](int nh, bf16x8* dst){
#pragma unroll
            for (int ks=0;ks<2;++ks){
                const int ch = (((ks*4+fq) ^ (fr&7))<<3);
#pragma unroll
                for (int j=0;j<2;++j)
                    dst[ks*2+j] = *(const bf16x8*)&bufB[(wn*64 + nh*32 + j*16 + fr)*64 + ch];
            }
        };
        auto QMFMA = [&](int mh, int nh, bf16x8* bArr){
            __builtin_amdgcn_s_setprio(1);
#pragma unroll
            for (int ks=0;ks<2;++ks)
#pragma unroll
            for (int j=0;j<4;++j)
#pragma unroll
            for (int jj=0;jj<2;++jj)
                acc[mh*4+j][nh*2+jj] = __builtin_amdgcn_mfma_f32_16x16x32_bf16(
                    aCur[ks*4+j], bArr[ks*2+jj], acc[mh*4+j][nh*2+jj], 0,0,0);
            __builtin_amdgcn_s_setprio(0);
            SCHED_FENCE();
        };

        // ---- phase 1: Q(0,0) ----
        if (t+1<nt) asm volatile("s_waitcnt vmcnt(6)" ::: "memory");
        else        asm volatile("s_waitcnt vmcnt(0)" ::: "memory");
        __builtin_amdgcn_s_barrier();
        SCHED_FENCE();
        if (t+1<nt) SB(t+1,1);
        SCHED_FENCE();
        LDA(0); LDB(0, b0);
        asm volatile("s_waitcnt lgkmcnt(0)" ::: "memory");
        SCHED_FENCE();
        QMFMA(0,0,b0);
        // ---- phase 2: Q(0,1) ----
        __builtin_amdgcn_s_barrier();
        SCHED_FENCE();
        if (t+2<nt) SA(t+2,0);
        SCHED_FENCE();
        LDB(1, b1);
        asm volatile("s_waitcnt lgkmcnt(0)" ::: "memory");
        SCHED_FENCE();
        QMFMA(0,1,b1);
        // ---- phase 3: Q(1,1) ----
        __builtin_amdgcn_s_barrier();
        SCHED_FENCE();
        if (t+2<nt) SB(t+2,0);
        SCHED_FENCE();
        LDA(1);
        asm volatile("s_waitcnt lgkmcnt(0)" ::: "memory");
        SCHED_FENCE();
        QMFMA(1,1,b1);
        // ---- phase 4: Q(1,0) ----
        __builtin_amdgcn_s_barrier();
        SCHED_FENCE();
        if (t+2<nt) SA(t+2,1);
        SCHED_FENCE();
        QMFMA(1,0,b0);
    }

#pragma unroll
    for (int mi=0;mi<8;++mi){
#pragma unroll
        for (int ni=0;ni<4;++ni){
            const int col = bx*256 + wn*64 + ni*16 + fr;
#pragma unroll
            for (int r=0;r<4;++r){
                const int row = by*256 + wm*128 + mi*16 + fq*4 + r;
                const float v = acc[mi][ni][r];
                const long ci = (long)row*ldc + col;
                if constexpr (EPI==EPI_F32)            ((float*)Cout)[ci] = v;
                else if constexpr (EPI==EPI_BIAS_F32)  ((float*)Cout)[ci] = v + bias[col];
                else                                   ((bf16*)Cout)[ci] = (bf16)v;
            }
        }
    }
}

// ---------------------------------------------------------------------------
// small kernels
// ---------------------------------------------------------------------------
__global__ void prep_kernel(const float* __restrict__ cs,
                            const float* __restrict__ W1, const float* __restrict__ b1,
                            const float* __restrict__ W2, const float* __restrict__ b2,
                            float* __restrict__ thrs)
{
    __shared__ float cp[1024];
    __shared__ float part[8][32];
    __shared__ float h[32];
    const int tid = threadIdx.x;
    for (int j = tid; j < 1024; j += 256){
        float s = 0.f;
#pragma unroll
        for (int r = 0; r < 8; r++) s += cs[r*1024 + j];
        cp[j] = s * 0.125f;
    }
    __syncthreads();
    const int t = tid & 31, g = tid >> 5;
    float p = 0.f;
    for (int j = g*128; j < g*128+128; j++) p += cp[j] * W1[j*32 + t];
    part[g][t] = p;
    __syncthreads();
    if (tid < 32){
        float s = b1[tid];
#pragma unroll
        for (int q=0;q<8;q++) s += part[q][tid];
        h[tid] = gelu_f(s);
    }
    __syncthreads();
    if (tid < 4){
        float z = b2[tid];
        for (int k=0;k<32;k++) z += h[k]*W2[k*4 + tid];
        thrs[tid] = sigm_f(z);
    }
    if (tid == 4) thrs[4] = 0.5f;   // betti threshold
}

__global__ void embed_kernel(const int* __restrict__ tok, const float* __restrict__ emb,
                             const float* __restrict__ pos, float* __restrict__ x)
{
    const long i = (long)blockIdx.x*256 + threadIdx.x;
    const int  d4 = i & 255;
    const long bt = i >> 8;
    const int  t  = (int)(bt & 2047);
    const int  token = tok[bt];
    f32x4 e = *(const f32x4*)(emb + (long)token*1024 + d4*4);
    f32x4 p = *(const f32x4*)(pos + (long)t*1024 + d4*4);
    *(f32x4*)(x + i*4) = e + p;
}

// batched f32->bf16 transpose: nb slices of [R][C] -> [C][R]
__global__ void transpose_f2b(const float* __restrict__ in, int ldin, long istr,
                              bf16* __restrict__ out, int ldout, long ostr,
                              int R, int C)
{
    __shared__ float tile[32][33];
    const int nbx = C >> 5, nby = R >> 5;
    const int per = nbx*nby;
    const int l  = blockIdx.x / per;
    const int rm = blockIdx.x % per;
    const int bx = rm % nbx, by = rm / nbx;
    const float* inl = in + (long)l*istr;
    bf16* outl = out + (long)l*ostr;
    const int tx = threadIdx.x & 31, ty = threadIdx.x >> 5;
#pragma unroll
    for (int i=0;i<32;i+=8)
        tile[ty+i][tx] = inl[(long)(by*32+ty+i)*ldin + bx*32+tx];
    __syncthreads();
#pragma unroll
    for (int i=0;i<32;i+=8)
        outl[(long)(bx*32+ty+i)*ldout + by*32+tx] = (bf16)tile[tx][ty+i];
}

__global__ void rownorm_kernel(const float* __restrict__ x, bf16* __restrict__ xn,
                               bf16* __restrict__ x0b, int ld0)
{
    const long t = blockIdx.x; const int tid = threadIdx.x;
    f32x4 v = *(const f32x4*)(x + t*1024 + tid*4);
    float s = v.x*v.x + v.y*v.y + v.z*v.z + v.w*v.w;
#pragma unroll
    for (int o=32;o>0;o>>=1) s += __shfl_down(s, o);
    __shared__ float red[4];
    if ((tid&63)==0) red[tid>>6] = s;
    __syncthreads();
    const float tot = red[0]+red[1]+red[2]+red[3];
    const float inv = 1.0f / fmaxf(sqrtf(tot), 1e-12f);
    bf16x4 a;
    a[0]=(bf16)(v.x*inv); a[1]=(bf16)(v.y*inv); a[2]=(bf16)(v.z*inv); a[3]=(bf16)(v.w*inv);
    *(bf16x4*)(xn + t*1024 + tid*4) = a;
    if (x0b){
        bf16x4 b;
        b[0]=(bf16)v.x; b[1]=(bf16)v.y; b[2]=(bf16)v.z; b[3]=(bf16)v.w;
        *(bf16x4*)(x0b + t*ld0 + tid*4) = b;
    }
}

__global__ void degree_kernel(const bf16* __restrict__ adj, float* __restrict__ deg)
{
    const long t = blockIdx.x; const int tid = threadIdx.x;
    bf16x8 v = *(const bf16x8*)(adj + t*2048 + tid*8);
    float s = 0.f;
#pragma unroll
    for (int j=0;j<8;j++) s += (float)v[j];
#pragma unroll
    for (int o=32;o>0;o>>=1) s += __shfl_down(s, o);
    __shared__ float red[4];
    if ((tid&63)==0) red[tid>>6] = s;
    __syncthreads();
    if (tid==0) deg[t] = red[0]+red[1]+red[2]+red[3];
}

__global__ void betti_kernel(const float* __restrict__ deg, float* __restrict__ betti)
{
    const int tid = threadIdx.x;
    float s = 0.f, c = 0.f;
#pragma unroll
    for (int i=0;i<8;i++){
        const float d = deg[tid*8 + i];
        s += d;  c += (d < 0.5f) ? 1.f : 0.f;
    }
#pragma unroll
    for (int o=32;o>0;o>>=1){ s += __shfl_down(s,o); c += __shfl_down(c,o); }
    __shared__ float ss[4], cc[4];
    if ((tid&63)==0){ ss[tid>>6]=s; cc[tid>>6]=c; }
    __syncthreads();
    if (tid==0){
        const float S = ss[0]+ss[1]+ss[2]+ss[3];
        const float C = cc[0]+cc[1]+cc[2]+cc[3];
        const float ne = 0.5f*S;
        const float b1 = ne - 2048.f + C + 1.f;
        betti[0] = C;
        betti[1] = b1 > 0.f ? b1 : 0.f;
    }
}

__global__ void b1eff_kernel(const float* __restrict__ ib1, const float* __restrict__ iW1,
                             const float* __restrict__ betti, float* __restrict__ out)
{
    const int j = blockIdx.x*256 + threadIdx.x;
    out[j] = ib1[j] + betti[0]*iW1[(long)1024*2048 + j] + betti[1]*iW1[(long)1025*2048 + j];
}

__global__ void ln_kernel(const float* __restrict__ y, const float* __restrict__ g,
                          const float* __restrict__ b, bf16* __restrict__ out)
{
    const long t = blockIdx.x; const int tid = threadIdx.x;
    f32x4 v = *(const f32x4*)(y + t*1024 + tid*4);
    float s  = v.x+v.y+v.z+v.w;
    float s2 = v.x*v.x+v.y*v.y+v.z*v.z+v.w*v.w;
#pragma unroll
    for (int o=32;o>0;o>>=1){ s += __shfl_down(s,o); s2 += __shfl_down(s2,o); }
    __shared__ float ss[4], qq[4];
    if ((tid&63)==0){ ss[tid>>6]=s; qq[tid>>6]=s2; }
    __syncthreads();
    const float S = ss[0]+ss[1]+ss[2]+ss[3], Q = qq[0]+qq[1]+qq[2]+qq[3];
    const float mu  = S * (1.f/1024.f);
    const float var = Q * (1.f/1024.f) - mu*mu;
    const float inv = rsqrtf(var + 1e-5f);
    f32x4 gv = *(const f32x4*)(g + tid*4);
    f32x4 bv = *(const f32x4*)(b + tid*4);
    bf16x4 o;
    o[0] = (bf16)((v.x - mu)*inv*gv.x + bv.x);
    o[1] = (bf16)((v.y - mu)*inv*gv.y + bv.y);
    o[2] = (bf16)((v.z - mu)*inv*gv.z + bv.z);
    o[3] = (bf16)((v.w - mu)*inv*gv.w + bv.w);
    *(bf16x4*)(out + t*1024 + tid*4) = o;
}

// ---------------------------------------------------------------------------
extern "C" void kernel_launch(void* const* d_in, const int* in_sizes, int n_in,
                              void* d_out, int out_size, void* d_ws, size_t ws_size,
                              hipStream_t stream)
{
    const int*   tokens = (const int*)  d_in[0];
    const float* cstate = (const float*)d_in[1];
    const float* embedW = (const float*)d_in[2];
    const float* posW   = (const float*)d_in[3];
    const float* thrW1  = (const float*)d_in[8];
    const float* thrb1  = (const float*)d_in[9];
    const float* thrW2  = (const float*)d_in[10];
    const float* thrb2  = (const float*)d_in[11];
    const float* simpW1 = (const float*)d_in[12];
    const float* simpb1 = (const float*)d_in[13];
    const float* simpW2 = (const float*)d_in[14];
    const float* simpb2 = (const float*)d_in[15];
    const float* intW1  = (const float*)d_in[16];
    const float* intb1  = (const float*)d_in[17];
    const float* intW2  = (const float*)d_in[18];
    const float* intb2  = (const float*)d_in[19];
    const float* lng    = (const float*)d_in[20];
    const float* lnb    = (const float*)d_in[21];
    const float* headW  = (const float*)d_in[22];
    float* out = (float*)d_out;

    size_t off = 0;
    auto carve = [&](size_t bytes) -> void* {
        void* p = (char*)d_ws + off;
        off += (bytes + 255) & ~(size_t)255;
        return p;
    };
    float* x_f32   = (float*)carve(16777216);
    bf16*  xn      = (bf16*) carve(4194304);
    bf16*  x0T     = (bf16*) carve(4194304);
    bf16*  comb    = (bf16*) carve(8388608);
    bf16*  adj     = (bf16*) carve(8388608);
    bf16*  h1      = (bf16*) carve(4194304);
    bf16*  xb      = (bf16*) carve(8388608);
    bf16*  w1T     = (bf16*) carve(16777216);
    bf16*  w2T     = (bf16*) carve(8388608);
    bf16*  i1T     = (bf16*) carve(4194304);
    bf16*  i2T     = (bf16*) carve(4194304);
    bf16*  hT      = (bf16*) carve(65536000);
    float* degree  = (float*)carve(8192);
    float* b1eff   = (float*)carve(8192);
    float* thrs    = (float*)carve(64);
    float* betti   = (float*)carve(64);
    bf16*  h2  = comb;
    float* yv  = x_f32;
    bf16*  xln = xn;

    const dim3 blk(256);
    const dim3 blk512(512);

    prep_kernel<<<1, blk, 0, stream>>>(cstate, thrW1, thrb1, thrW2, thrb2, thrs);
    embed_kernel<<<4096, blk, 0, stream>>>(tokens, embedW, posW, x_f32);

    // weight transposes (batched): w1T x4, w2T x4, then i1T, i2T, hT
    transpose_f2b<<<4*(1024/32)*(2048/32), blk, 0, stream>>>(
        simpW1, 1024, (long)2048*1024, w1T, 2048, (long)1024*2048, 2048, 1024);
    transpose_f2b<<<4*(1024/32)*(1024/32), blk, 0, stream>>>(
        simpW2, 1024, (long)1024*1024, w2T, 1024, (long)1024*1024, 1024, 1024);
    transpose_f2b<<<(2048/32)*(1024/32), blk, 0, stream>>>(
        intW1, 2048, 0, i1T, 1024, 0, 1024, 2048);
    transpose_f2b<<<(1024/32)*(2048/32), blk, 0, stream>>>(
        intW2, 1024, 0, i2T, 2048, 0, 2048, 1024);
    transpose_f2b<<<(32000/32)*(1024/32), blk, 0, stream>>>(
        headW, 32000, 0, hT, 1024, 0, 1024, 32000);

    for (int l=0;l<4;l++){
        rownorm_kernel<<<2048, blk, 0, stream>>>(x_f32, xn, comb, 2048);
        transpose_f2b<<<(1024/32)*(2048/32), blk, 0, stream>>>(
            x_f32, 1024, 0, x0T, 2048, 0, 2048, 1024);
        gemm_p<128,128,2,2,2,1,EPI_ADJ><<<136, blk, 0, stream>>>(
            xn, xn, 2048, 2048, 1024, adj, 2048, nullptr, thrs, l, nullptr, nullptr, nullptr);
        mirror_kernel<<<1920, blk, 0, stream>>>(adj);
        gemm_p<64,128,2,2,3,0,EPI_BF16><<<32*8, blk, 0, stream>>>(
            adj, x0T, 2048, 1024, 2048, comb + 1024, 2048, nullptr, nullptr, 0, nullptr, nullptr, nullptr);
        gemm_p<64,128,2,2,3,0,EPI_GELU_BIAS><<<32*8, blk, 0, stream>>>(
            comb, w1T + (long)l*1024*2048, 2048, 1024, 2048, h1, 1024,
            simpb1 + l*1024, nullptr, 0, nullptr, nullptr, nullptr);
        if (l < 3)
            gemm_p<64,128,2,2,3,0,EPI_XUPD><<<32*8, blk, 0, stream>>>(
                h1, w2T + (long)l*1024*1024, 2048, 1024, 1024, nullptr, 1024,
                simpb2 + l*1024, nullptr, 0, x_f32, x_f32 + (long)2048*1024, nullptr);
        else
            gemm_p<64,128,2,2,3,0,EPI_XUPDB><<<32*8, blk, 0, stream>>>(
                h1, w2T + (long)l*1024*1024, 2048, 1024, 1024, nullptr, 1024,
                simpb2 + l*1024, nullptr, 0, x_f32, x_f32 + (long)2048*1024, xb);
    }

    rownorm_kernel<<<2048, blk, 0, stream>>>(x_f32, xn, nullptr, 0);
    gemm_p<128,128,2,2,2,1,EPI_ADJ><<<136, blk, 0, stream>>>(
        xn, xn, 2048, 2048, 1024, adj, 2048, nullptr, thrs, 4, nullptr, nullptr, nullptr);
    mirror_kernel<<<1920, blk, 0, stream>>>(adj);
    degree_kernel<<<2048, blk, 0, stream>>>(adj, degree);
    betti_kernel<<<1, blk, 0, stream>>>(degree, betti);
    b1eff_kernel<<<8, blk, 0, stream>>>(intb1, intW1, betti, b1eff);

    gemm_p<128,128,2,2,2,0,EPI_GELU_BIAS><<<32*16, blk, 0, stream>>>(
        xb, i1T, 4096, 2048, 1024, h2, 2048, b1eff, nullptr, 0, nullptr, nullptr, nullptr);
    gemm_p<128,128,2,2,2,0,EPI_BIAS_F32><<<32*8, blk, 0, stream>>>(
        h2, i2T, 4096, 1024, 2048, yv, 1024, intb2, nullptr, 0, nullptr, nullptr, nullptr);
    ln_kernel<<<4096, blk, 0, stream>>>(yv, lng, lnb, xln);
    gemm8<EPI_F32><<<16*125, blk512, 0, stream>>>(
        xln, hT, 4096, 32000, 1024, out, 32000, nullptr);
}

// Round 14
// 859.859 us; speedup vs baseline: 1.0159x; 1.0159x over previous
//
#include <hip/hip_runtime.h>

typedef __bf16 bf16;
using bf16x8 = __attribute__((ext_vector_type(8))) __bf16;
using bf16x4 = __attribute__((ext_vector_type(4))) __bf16;
using f32x4  = __attribute__((ext_vector_type(4))) float;

#define DEV __device__ __forceinline__
#define SCHED_FENCE() __builtin_amdgcn_sched_barrier(0)

DEV float gelu_f(float x){ return 0.5f*x*(1.0f+erff(x*0.7071067811865475f)); }
DEV float sigm_f(float x){ return 1.0f/(1.0f+expf(-x)); }

DEV void gload16(const bf16* g, bf16* l){
    __builtin_amdgcn_global_load_lds(
        (const __attribute__((address_space(1))) void*)g,
        (__attribute__((address_space(3))) void*)l, 16, 0, 0);
}

enum { EPI_ADJ=0, EPI_BF16=1, EPI_GELU_BIAS=2, EPI_XUPD=3, EPI_BIAS_F32=4, EPI_F32=5, EPI_XUPDB=6 };

// ---------------------------------------------------------------------------
// r5-proven GEMM: BK=64, 2 LDS buffers, counted vmcnt, both-sides swizzle.
// ---------------------------------------------------------------------------
template<int BM,int BN,int WM,int WN,int MINW,int EPI>
__global__ __launch_bounds__(WM*WN*64, MINW)
void gemm_p(const bf16* __restrict__ A, const bf16* __restrict__ B,
            int M, int N, int K, void* __restrict__ Cout, int ldc,
            const float* __restrict__ bias, const float* __restrict__ scal, int sidx,
            float* __restrict__ xu0, float* __restrict__ xu1, bf16* __restrict__ xbp)
{
    constexpr int THREADS = WM*WN*64;
    constexpr int MR = BM/WM/16, NR = BN/WN/16;
    constexpr int ATILE = BM*64, BTILE = BN*64;
    constexpr int RR = THREADS/8;
    constexpr int VM = (BM+BN)/RR;
    __shared__ bf16 sm[2*(ATILE+BTILE)];

    const int nbm = M/BM, nbn = N/BN;
    const int nwg = nbm*nbn;
    int wg = blockIdx.x;
    wg = (wg&7)*(nwg>>3) + (wg>>3);
    const int by = wg % nbm, bx = wg / nbm;
    const int tid = threadIdx.x, lane = tid&63, wid = tid>>6;
    const int wm = wid / WN, wn = wid % WN;
    const int fr = lane&15, fq = lane>>4;

    const bf16* Ab = A + (long)(by*BM + (tid>>3))*K + (((tid&7) ^ ((tid>>3)&7))<<3);
    const bf16* Bb = B + (long)(bx*BN + (tid>>3))*K + (((tid&7) ^ ((tid>>3)&7))<<3);

    auto STAGE = [&](int tt, int cb){
        bf16* d = sm + cb*(ATILE+BTILE) + wid*512;
        const long ko = (long)tt*64;
#pragma unroll
        for (int g=0; g<BM/RR; ++g)
            gload16(Ab + (long)g*RR*K + ko, d + g*RR*64);
#pragma unroll
        for (int g=0; g<BN/RR; ++g)
            gload16(Bb + (long)g*RR*K + ko, d + ATILE + g*RR*64);
    };

    f32x4 acc[MR][NR] = {};
    const int nt = K >> 6;

    STAGE(0,0);
    STAGE(1,1);

    for (int t=0; t<nt; ++t){
        const bf16* bufA = sm + (t&1)*(ATILE+BTILE);
        const bf16* bufB = bufA + ATILE;
        if (t+1<nt){
            if constexpr (VM==6)      asm volatile("s_waitcnt vmcnt(6)" ::: "memory");
            else if constexpr (VM==8) asm volatile("s_waitcnt vmcnt(8)" ::: "memory");
            else                      asm volatile("s_waitcnt vmcnt(0)" ::: "memory");
        } else {
            asm volatile("s_waitcnt vmcnt(0)" ::: "memory");
        }
        __builtin_amdgcn_s_barrier();
        __builtin_amdgcn_sched_barrier(0);
#pragma unroll
        for (int ks=0; ks<2; ++ks){
            bf16x8 af[MR], bv[NR];
            const int ch = (((ks*4+fq) ^ (fr&7))<<3);
#pragma unroll
            for (int j=0;j<MR;++j)
                af[j] = *(const bf16x8*)&bufA[(wm*(MR*16) + j*16 + fr)*64 + ch];
#pragma unroll
            for (int j=0;j<NR;++j)
                bv[j] = *(const bf16x8*)&bufB[(wn*(NR*16) + j*16 + fr)*64 + ch];
            __builtin_amdgcn_s_setprio(1);
#pragma unroll
            for (int mi=0;mi<MR;++mi)
#pragma unroll
            for (int ni=0;ni<NR;++ni)
                acc[mi][ni] = __builtin_amdgcn_mfma_f32_16x16x32_bf16(
                    af[mi], bv[ni], acc[mi][ni], 0,0,0);
            __builtin_amdgcn_s_setprio(0);
        }
        asm volatile("s_waitcnt lgkmcnt(0)" ::: "memory");
        __builtin_amdgcn_s_barrier();
        if (t+2<nt) STAGE(t+2, t&1);
    }

    float thr = 0.f;
    if constexpr (EPI==EPI_ADJ) thr = scal[sidx];

#pragma unroll
    for (int mi=0;mi<MR;++mi){
#pragma unroll
        for (int ni=0;ni<NR;++ni){
            const int col = bx*BN + wn*(NR*16) + ni*16 + fr;
#pragma unroll
            for (int r=0;r<4;++r){
                const int row = by*BM + wm*(MR*16) + mi*16 + fq*4 + r;
                const float v = acc[mi][ni][r];
                const long ci = (long)row*ldc + col;
                if constexpr (EPI==EPI_ADJ)       ((bf16*)Cout)[ci] = (bf16)sigm_f(10.f*(v - thr));
                else if constexpr (EPI==EPI_BF16) ((bf16*)Cout)[ci] = (bf16)v;
                else if constexpr (EPI==EPI_GELU_BIAS) ((bf16*)Cout)[ci] = (bf16)gelu_f(v + bias[col]);
                else if constexpr (EPI==EPI_BIAS_F32)  ((float*)Cout)[ci] = v + bias[col];
                else if constexpr (EPI==EPI_F32)       ((float*)Cout)[ci] = v;
                else if constexpr (EPI==EPI_XUPD){
                    const float u = 0.2f*(v + bias[col]);
                    xu0[ci] += u;  xu1[ci] += u;
                }
                else if constexpr (EPI==EPI_XUPDB){
                    const float u = 0.2f*(v + bias[col]);
                    const float n0 = xu0[ci] + u, n1 = xu1[ci] + u;
                    xu0[ci] = n0;  xu1[ci] = n1;
                    xbp[ci] = (bf16)n0;
                    xbp[ci + (long)2048*1024] = (bf16)n1;
                }
            }
        }
    }
}

// ---------------------------------------------------------------------------
// 8-phase head GEMM (r11-verified schedule): 256x256, quadrant phases, phase-
// aligned A staging units, vmcnt(6) steady state, full fencing.
// Block ordering r14: PLAIN M-inner, NO XCD swizzle — consecutive wg (which
// dispatch round-robin across XCDs) share the same B panel, so the chip-wide
// instantaneous working set is ~16 MB (16 bx panels + all A) and B panels are
// fetched ~once via the shared L3 (r12's per-XCD full-B sweep hit 530 MB).
// ---------------------------------------------------------------------------
template<int EPI>
__global__ __launch_bounds__(512, 2)
void gemm8(const bf16* __restrict__ A, const bf16* __restrict__ B,
           int M, int N, int K, void* __restrict__ Cout, int ldc,
           const float* __restrict__ bias)
{
    __shared__ bf16 sm[65536];
    const int nbm = M>>8;
    const int wg = blockIdx.x;
    const int by = wg % nbm, bx = wg / nbm;      // M-inner, no swizzle
    const int tid = threadIdx.x, lane = tid&63, wid = tid>>6;
    const int wm = wid>>2, wn = wid&3;
    const int fr = lane&15, fq = lane>>4;

    const bf16* Ag = A + (long)(by*256 + (tid>>3))*K + (((tid&7) ^ ((tid>>3)&7))<<3);
    const bf16* Bg = B + (long)(bx*256 + (tid>>3))*K + (((tid&7) ^ ((tid>>3)&7))<<3);

    auto SA = [&](int tt, int h){
        bf16* d = sm + (tt&1)*32768 + wid*512;
        const long ko = (long)tt*64;
        gload16(Ag + (long)(h*64)*K + ko,       d + h*4096);
        gload16(Ag + (long)(128+h*64)*K + ko,   d + 8192 + h*4096);
    };
    auto SB = [&](int tt, int h){
        bf16* d = sm + (tt&1)*32768 + 16384 + wid*512;
        const long ko = (long)tt*64;
#pragma unroll
        for (int g=0; g<2; ++g)
            gload16(Bg + (long)(h*2+g)*64*K + ko, d + (h*2+g)*4096);
    };

    f32x4 acc[8][4] = {};
    bf16x8 aCur[8], b0[4], b1[4];
    const int nt = K >> 6;

    SA(0,0); SB(0,0); SA(0,1); SB(0,1);
    SA(1,0); SB(1,0); SA(1,1);
    SCHED_FENCE();

    for (int t=0; t<nt; ++t){
        const bf16* bufA = sm + (t&1)*32768;
        const bf16* bufB = bufA + 16384;

        auto LDA = [&](int mh){
#pragma unroll
            for (int ks=0;ks<2;++ks){
                const int ch = (((ks*4+fq) ^ (fr&7))<<3);
#pragma unroll
                for (int j=0;j<4;++j)
                    aCur[ks*4+j] = *(const bf16x8*)&bufA[(wm*128 + mh*64 + j*16 + fr)*64 + ch];
            }
        };
        auto LDB = [&](int nh, bf16x8* dst){
#pragma unroll
            for (int ks=0;ks<2;++ks){
                const int ch = (((ks*4+fq) ^ (fr&7))<<3);
#pragma unroll
                for (int j=0;j<2;++j)
                    dst[ks*2+j] = *(const bf16x8*)&bufB[(wn*64 + nh*32 + j*16 + fr)*64 + ch];
            }
        };
        auto QMFMA = [&](int mh, int nh, bf16x8* bArr){
            __builtin_amdgcn_s_setprio(1);
#pragma unroll
            for (int ks=0;ks<2;++ks)
#pragma unroll
            for (int j=0;j<4;++j)
#pragma unroll
            for (int jj=0;jj<2;++jj)
                acc[mh*4+j][nh*2+jj] = __builtin_amdgcn_mfma_f32_16x16x32_bf16(
                    aCur[ks*4+j], bArr[ks*2+jj], acc[mh*4+j][nh*2+jj], 0,0,0);
            __builtin_amdgcn_s_setprio(0);
            SCHED_FENCE();
        };

        // ---- phase 1: Q(0,0) ----
        if (t+1<nt) asm volatile("s_waitcnt vmcnt(6)" ::: "memory");
        else        asm volatile("s_waitcnt vmcnt(0)" ::: "memory");
        __builtin_amdgcn_s_barrier();
        SCHED_FENCE();
        if (t+1<nt) SB(t+1,1);
        SCHED_FENCE();
        LDA(0); LDB(0, b0);
        asm volatile("s_waitcnt lgkmcnt(0)" ::: "memory");
        SCHED_FENCE();
        QMFMA(0,0,b0);
        // ---- phase 2: Q(0,1) ----
        __builtin_amdgcn_s_barrier();
        SCHED_FENCE();
        if (t+2<nt) SA(t+2,0);
        SCHED_FENCE();
        LDB(1, b1);
        asm volatile("s_waitcnt lgkmcnt(0)" ::: "memory");
        SCHED_FENCE();
        QMFMA(0,1,b1);
        // ---- phase 3: Q(1,1) ----
        __builtin_amdgcn_s_barrier();
        SCHED_FENCE();
        if (t+2<nt) SB(t+2,0);
        SCHED_FENCE();
        LDA(1);
        asm volatile("s_waitcnt lgkmcnt(0)" ::: "memory");
        SCHED_FENCE();
        QMFMA(1,1,b1);
        // ---- phase 4: Q(1,0) ----
        __builtin_amdgcn_s_barrier();
        SCHED_FENCE();
        if (t+2<nt) SA(t+2,1);
        SCHED_FENCE();
        QMFMA(1,0,b0);
    }

#pragma unroll
    for (int mi=0;mi<8;++mi){
#pragma unroll
        for (int ni=0;ni<4;++ni){
            const int col = bx*256 + wn*64 + ni*16 + fr;
#pragma unroll
            for (int r=0;r<4;++r){
                const int row = by*256 + wm*128 + mi*16 + fq*4 + r;
                const float v = acc[mi][ni][r];
                const long ci = (long)row*ldc + col;
                if constexpr (EPI==EPI_F32)            ((float*)Cout)[ci] = v;
                else if constexpr (EPI==EPI_BIAS_F32)  ((float*)Cout)[ci] = v + bias[col];
                else                                   ((bf16*)Cout)[ci] = (bf16)v;
            }
        }
    }
}

// ---------------------------------------------------------------------------
// small kernels
// ---------------------------------------------------------------------------
__global__ void prep_kernel(const float* __restrict__ cs,
                            const float* __restrict__ W1, const float* __restrict__ b1,
                            const float* __restrict__ W2, const float* __restrict__ b2,
                            float* __restrict__ thrs)
{
    __shared__ float cp[1024];
    __shared__ float part[8][32];
    __shared__ float h[32];
    const int tid = threadIdx.x;
    for (int j = tid; j < 1024; j += 256){
        float s = 0.f;
#pragma unroll
        for (int r = 0; r < 8; r++) s += cs[r*1024 + j];
        cp[j] = s * 0.125f;
    }
    __syncthreads();
    const int t = tid & 31, g = tid >> 5;
    float p = 0.f;
    for (int j = g*128; j < g*128+128; j++) p += cp[j] * W1[j*32 + t];
    part[g][t] = p;
    __syncthreads();
    if (tid < 32){
        float s = b1[tid];
#pragma unroll
        for (int q=0;q<8;q++) s += part[q][tid];
        h[tid] = gelu_f(s);
    }
    __syncthreads();
    if (tid < 4){
        float z = b2[tid];
        for (int k=0;k<32;k++) z += h[k]*W2[k*4 + tid];
        thrs[tid] = sigm_f(z);
    }
    if (tid == 4) thrs[4] = 0.5f;   // betti threshold
}

__global__ void embed_kernel(const int* __restrict__ tok, const float* __restrict__ emb,
                             const float* __restrict__ pos, float* __restrict__ x)
{
    const long i = (long)blockIdx.x*256 + threadIdx.x;
    const int  d4 = i & 255;
    const long bt = i >> 8;
    const int  t  = (int)(bt & 2047);
    const int  token = tok[bt];
    f32x4 e = *(const f32x4*)(emb + (long)token*1024 + d4*4);
    f32x4 p = *(const f32x4*)(pos + (long)t*1024 + d4*4);
    *(f32x4*)(x + i*4) = e + p;
}

// batched f32->bf16 transpose: nb slices of [R][C] -> [C][R]
__global__ void transpose_f2b(const float* __restrict__ in, int ldin, long istr,
                              bf16* __restrict__ out, int ldout, long ostr,
                              int R, int C)
{
    __shared__ float tile[32][33];
    const int nbx = C >> 5, nby = R >> 5;
    const int per = nbx*nby;
    const int l  = blockIdx.x / per;
    const int rm = blockIdx.x % per;
    const int bx = rm % nbx, by = rm / nbx;
    const float* inl = in + (long)l*istr;
    bf16* outl = out + (long)l*ostr;
    const int tx = threadIdx.x & 31, ty = threadIdx.x >> 5;
#pragma unroll
    for (int i=0;i<32;i+=8)
        tile[ty+i][tx] = inl[(long)(by*32+ty+i)*ldin + bx*32+tx];
    __syncthreads();
#pragma unroll
    for (int i=0;i<32;i+=8)
        outl[(long)(bx*32+ty+i)*ldout + by*32+tx] = (bf16)tile[tx][ty+i];
}

__global__ void rownorm_kernel(const float* __restrict__ x, bf16* __restrict__ xn,
                               bf16* __restrict__ x0b, int ld0)
{
    const long t = blockIdx.x; const int tid = threadIdx.x;
    f32x4 v = *(const f32x4*)(x + t*1024 + tid*4);
    float s = v.x*v.x + v.y*v.y + v.z*v.z + v.w*v.w;
#pragma unroll
    for (int o=32;o>0;o>>=1) s += __shfl_down(s, o);
    __shared__ float red[4];
    if ((tid&63)==0) red[tid>>6] = s;
    __syncthreads();
    const float tot = red[0]+red[1]+red[2]+red[3];
    const float inv = 1.0f / fmaxf(sqrtf(tot), 1e-12f);
    bf16x4 a;
    a[0]=(bf16)(v.x*inv); a[1]=(bf16)(v.y*inv); a[2]=(bf16)(v.z*inv); a[3]=(bf16)(v.w*inv);
    *(bf16x4*)(xn + t*1024 + tid*4) = a;
    if (x0b){
        bf16x4 b;
        b[0]=(bf16)v.x; b[1]=(bf16)v.y; b[2]=(bf16)v.z; b[3]=(bf16)v.w;
        *(bf16x4*)(x0b + t*ld0 + tid*4) = b;
    }
}

__global__ void degree_kernel(const bf16* __restrict__ adj, float* __restrict__ deg)
{
    const long t = blockIdx.x; const int tid = threadIdx.x;
    bf16x8 v = *(const bf16x8*)(adj + t*2048 + tid*8);
    float s = 0.f;
#pragma unroll
    for (int j=0;j<8;j++) s += (float)v[j];
#pragma unroll
    for (int o=32;o>0;o>>=1) s += __shfl_down(s, o);
    __shared__ float red[4];
    if ((tid&63)==0) red[tid>>6] = s;
    __syncthreads();
    if (tid==0) deg[t] = red[0]+red[1]+red[2]+red[3];
}

__global__ void betti_kernel(const float* __restrict__ deg, float* __restrict__ betti)
{
    const int tid = threadIdx.x;
    float s = 0.f, c = 0.f;
#pragma unroll
    for (int i=0;i<8;i++){
        const float d = deg[tid*8 + i];
        s += d;  c += (d < 0.5f) ? 1.f : 0.f;
    }
#pragma unroll
    for (int o=32;o>0;o>>=1){ s += __shfl_down(s,o); c += __shfl_down(c,o); }
    __shared__ float ss[4], cc[4];
    if ((tid&63)==0){ ss[tid>>6]=s; cc[tid>>6]=c; }
    __syncthreads();
    if (tid==0){
        const float S = ss[0]+ss[1]+ss[2]+ss[3];
        const float C = cc[0]+cc[1]+cc[2]+cc[3];
        const float ne = 0.5f*S;
        const float b1 = ne - 2048.f + C + 1.f;
        betti[0] = C;
        betti[1] = b1 > 0.f ? b1 : 0.f;
    }
}

__global__ void b1eff_kernel(const float* __restrict__ ib1, const float* __restrict__ iW1,
                             const float* __restrict__ betti, float* __restrict__ out)
{
    const int j = blockIdx.x*256 + threadIdx.x;
    out[j] = ib1[j] + betti[0]*iW1[(long)1024*2048 + j] + betti[1]*iW1[(long)1025*2048 + j];
}

__global__ void ln_kernel(const float* __restrict__ y, const float* __restrict__ g,
                          const float* __restrict__ b, bf16* __restrict__ out)
{
    const long t = blockIdx.x; const int tid = threadIdx.x;
    f32x4 v = *(const f32x4*)(y + t*1024 + tid*4);
    float s  = v.x+v.y+v.z+v.w;
    float s2 = v.x*v.x+v.y*v.y+v.z*v.z+v.w*v.w;
#pragma unroll
    for (int o=32;o>0;o>>=1){ s += __shfl_down(s,o); s2 += __shfl_down(s2,o); }
    __shared__ float ss[4], qq[4];
    if ((tid&63)==0){ ss[tid>>6]=s; qq[tid>>6]=s2; }
    __syncthreads();
    const float S = ss[0]+ss[1]+ss[2]+ss[3], Q = qq[0]+qq[1]+qq[2]+qq[3];
    const float mu  = S * (1.f/1024.f);
    const float var = Q * (1.f/1024.f) - mu*mu;
    const float inv = rsqrtf(var + 1e-5f);
    f32x4 gv = *(const f32x4*)(g + tid*4);
    f32x4 bv = *(const f32x4*)(b + tid*4);
    bf16x4 o;
    o[0] = (bf16)((v.x - mu)*inv*gv.x + bv.x);
    o[1] = (bf16)((v.y - mu)*inv*gv.y + bv.y);
    o[2] = (bf16)((v.z - mu)*inv*gv.z + bv.z);
    o[3] = (bf16)((v.w - mu)*inv*gv.w + bv.w);
    *(bf16x4*)(out + t*1024 + tid*4) = o;
}

// ---------------------------------------------------------------------------
extern "C" void kernel_launch(void* const* d_in, const int* in_sizes, int n_in,
                              void* d_out, int out_size, void* d_ws, size_t ws_size,
                              hipStream_t stream)
{
    const int*   tokens = (const int*)  d_in[0];
    const float* cstate = (const float*)d_in[1];
    const float* embedW = (const float*)d_in[2];
    const float* posW   = (const float*)d_in[3];
    const float* thrW1  = (const float*)d_in[8];
    const float* thrb1  = (const float*)d_in[9];
    const float* thrW2  = (const float*)d_in[10];
    const float* thrb2  = (const float*)d_in[11];
    const float* simpW1 = (const float*)d_in[12];
    const float* simpb1 = (const float*)d_in[13];
    const float* simpW2 = (const float*)d_in[14];
    const float* simpb2 = (const float*)d_in[15];
    const float* intW1  = (const float*)d_in[16];
    const float* intb1  = (const float*)d_in[17];
    const float* intW2  = (const float*)d_in[18];
    const float* intb2  = (const float*)d_in[19];
    const float* lng    = (const float*)d_in[20];
    const float* lnb    = (const float*)d_in[21];
    const float* headW  = (const float*)d_in[22];
    float* out = (float*)d_out;

    size_t off = 0;
    auto carve = [&](size_t bytes) -> void* {
        void* p = (char*)d_ws + off;
        off += (bytes + 255) & ~(size_t)255;
        return p;
    };
    float* x_f32   = (float*)carve(16777216);
    bf16*  xn      = (bf16*) carve(4194304);
    bf16*  x0T     = (bf16*) carve(4194304);
    bf16*  comb    = (bf16*) carve(8388608);
    bf16*  adj     = (bf16*) carve(8388608);
    bf16*  h1      = (bf16*) carve(4194304);
    bf16*  xb      = (bf16*) carve(8388608);
    bf16*  w1T     = (bf16*) carve(16777216);
    bf16*  w2T     = (bf16*) carve(8388608);
    bf16*  i1T     = (bf16*) carve(4194304);
    bf16*  i2T     = (bf16*) carve(4194304);
    bf16*  hT      = (bf16*) carve(65536000);
    float* degree  = (float*)carve(8192);
    float* b1eff   = (float*)carve(8192);
    float* thrs    = (float*)carve(64);
    float* betti   = (float*)carve(64);
    bf16*  h2  = comb;
    float* yv  = x_f32;
    bf16*  xln = xn;

    const dim3 blk(256);
    const dim3 blk512(512);

    prep_kernel<<<1, blk, 0, stream>>>(cstate, thrW1, thrb1, thrW2, thrb2, thrs);
    embed_kernel<<<4096, blk, 0, stream>>>(tokens, embedW, posW, x_f32);

    // weight transposes (batched): w1T x4, w2T x4, then i1T, i2T, hT
    transpose_f2b<<<4*(1024/32)*(2048/32), blk, 0, stream>>>(
        simpW1, 1024, (long)2048*1024, w1T, 2048, (long)1024*2048, 2048, 1024);
    transpose_f2b<<<4*(1024/32)*(1024/32), blk, 0, stream>>>(
        simpW2, 1024, (long)1024*1024, w2T, 1024, (long)1024*1024, 1024, 1024);
    transpose_f2b<<<(2048/32)*(1024/32), blk, 0, stream>>>(
        intW1, 2048, 0, i1T, 1024, 0, 1024, 2048);
    transpose_f2b<<<(1024/32)*(2048/32), blk, 0, stream>>>(
        intW2, 1024, 0, i2T, 2048, 0, 2048, 1024);
    transpose_f2b<<<(32000/32)*(1024/32), blk, 0, stream>>>(
        headW, 32000, 0, hT, 1024, 0, 1024, 32000);

    for (int l=0;l<4;l++){
        rownorm_kernel<<<2048, blk, 0, stream>>>(x_f32, xn, comb, 2048);
        transpose_f2b<<<(1024/32)*(2048/32), blk, 0, stream>>>(
            x_f32, 1024, 0, x0T, 2048, 0, 2048, 1024);
        gemm_p<128,128,2,2,2,EPI_ADJ><<<16*16, blk, 0, stream>>>(
            xn, xn, 2048, 2048, 1024, adj, 2048, nullptr, thrs, l, nullptr, nullptr, nullptr);
        gemm_p<64,128,2,2,3,EPI_BF16><<<32*8, blk, 0, stream>>>(
            adj, x0T, 2048, 1024, 2048, comb + 1024, 2048, nullptr, nullptr, 0, nullptr, nullptr, nullptr);
        gemm_p<64,128,2,2,3,EPI_GELU_BIAS><<<32*8, blk, 0, stream>>>(
            comb, w1T + (long)l*1024*2048, 2048, 1024, 2048, h1, 1024,
            simpb1 + l*1024, nullptr, 0, nullptr, nullptr, nullptr);
        if (l < 3)
            gemm_p<64,128,2,2,3,EPI_XUPD><<<32*8, blk, 0, stream>>>(
                h1, w2T + (long)l*1024*1024, 2048, 1024, 1024, nullptr, 1024,
                simpb2 + l*1024, nullptr, 0, x_f32, x_f32 + (long)2048*1024, nullptr);
        else
            gemm_p<64,128,2,2,3,EPI_XUPDB><<<32*8, blk, 0, stream>>>(
                h1, w2T + (long)l*1024*1024, 2048, 1024, 1024, nullptr, 1024,
                simpb2 + l*1024, nullptr, 0, x_f32, x_f32 + (long)2048*1024, xb);
    }

    rownorm_kernel<<<2048, blk, 0, stream>>>(x_f32, xn, nullptr, 0);
    gemm_p<128,128,2,2,2,EPI_ADJ><<<16*16, blk, 0, stream>>>(
        xn, xn, 2048, 2048, 1024, adj, 2048, nullptr, thrs, 4, nullptr, nullptr, nullptr);
    degree_kernel<<<2048, blk, 0, stream>>>(adj, degree);
    betti_kernel<<<1, blk, 0, stream>>>(degree, betti);
    b1eff_kernel<<<8, blk, 0, stream>>>(intb1, intW1, betti, b1eff);

    gemm_p<128,128,2,2,2,EPI_GELU_BIAS><<<32*16, blk, 0, stream>>>(
        xb, i1T, 4096, 2048, 1024, h2, 2048, b1eff, nullptr, 0, nullptr, nullptr, nullptr);
    gemm_p<128,128,2,2,2,EPI_BIAS_F32><<<32*8, blk, 0, stream>>>(
        h2, i2T, 4096, 1024, 2048, yv, 1024, intb2, nullptr, 0, nullptr, nullptr, nullptr);
    ln_kernel<<<4096, blk, 0, stream>>>(yv, lng, lnb, xln);
    gemm8<EPI_F32><<<16*125, blk512, 0, stream>>>(
        xln, hT, 4096, 32000, 1024, out, 32000, nullptr);
}

// Round 15
// 812.449 us; speedup vs baseline: 1.0751x; 1.0584x over previous
//
#include <hip/hip_runtime.h>

typedef __bf16 bf16;
using bf16x8 = __attribute__((ext_vector_type(8))) __bf16;
using bf16x4 = __attribute__((ext_vector_type(4))) __bf16;
using f32x4  = __attribute__((ext_vector_type(4))) float;

#define DEV __device__ __forceinline__
#define SCHED_FENCE() __builtin_amdgcn_sched_barrier(0)

DEV float gelu_f(float x){ return 0.5f*x*(1.0f+erff(x*0.7071067811865475f)); }
DEV float sigm_f(float x){ return 1.0f/(1.0f+expf(-x)); }

DEV void gload16(const bf16* g, bf16* l){
    __builtin_amdgcn_global_load_lds(
        (const __attribute__((address_space(1))) void*)g,
        (__attribute__((address_space(3))) void*)l, 16, 0, 0);
}

enum { EPI_ADJ=0, EPI_BF16=1, EPI_GELU_BIAS=2, EPI_XUPD=3, EPI_BIAS_F32=4, EPI_F32=5,
       EPI_XUPDB=6, EPI_XUPDT=7 };

// ---------------------------------------------------------------------------
// r5-proven GEMM: BK=64, 2 LDS buffers, counted vmcnt, both-sides swizzle.
// EPI_XUPDT: x += update (both batches) AND write next-level comb-half (bf16
// x0) + x0T (transposed x0) straight from the epilogue registers.
// ---------------------------------------------------------------------------
template<int BM,int BN,int WM,int WN,int MINW,int EPI>
__global__ __launch_bounds__(WM*WN*64, MINW)
void gemm_p(const bf16* __restrict__ A, const bf16* __restrict__ B,
            int M, int N, int K, void* __restrict__ Cout, int ldc,
            const float* __restrict__ bias, const float* __restrict__ scal, int sidx,
            float* __restrict__ xu0, float* __restrict__ xu1, bf16* __restrict__ xbp)
{
    constexpr int THREADS = WM*WN*64;
    constexpr int MR = BM/WM/16, NR = BN/WN/16;
    constexpr int ATILE = BM*64, BTILE = BN*64;
    constexpr int RR = THREADS/8;
    constexpr int VM = (BM+BN)/RR;
    __shared__ bf16 sm[2*(ATILE+BTILE)];

    const int nbm = M/BM, nbn = N/BN;
    const int nwg = nbm*nbn;
    int wg = blockIdx.x;
    wg = (wg&7)*(nwg>>3) + (wg>>3);
    const int by = wg % nbm, bx = wg / nbm;
    const int tid = threadIdx.x, lane = tid&63, wid = tid>>6;
    const int wm = wid / WN, wn = wid % WN;
    const int fr = lane&15, fq = lane>>4;

    const bf16* Ab = A + (long)(by*BM + (tid>>3))*K + (((tid&7) ^ ((tid>>3)&7))<<3);
    const bf16* Bb = B + (long)(bx*BN + (tid>>3))*K + (((tid&7) ^ ((tid>>3)&7))<<3);

    auto STAGE = [&](int tt, int cb){
        bf16* d = sm + cb*(ATILE+BTILE) + wid*512;
        const long ko = (long)tt*64;
#pragma unroll
        for (int g=0; g<BM/RR; ++g)
            gload16(Ab + (long)g*RR*K + ko, d + g*RR*64);
#pragma unroll
        for (int g=0; g<BN/RR; ++g)
            gload16(Bb + (long)g*RR*K + ko, d + ATILE + g*RR*64);
    };

    f32x4 acc[MR][NR] = {};
    const int nt = K >> 6;

    STAGE(0,0);
    STAGE(1,1);

    for (int t=0; t<nt; ++t){
        const bf16* bufA = sm + (t&1)*(ATILE+BTILE);
        const bf16* bufB = bufA + ATILE;
        if (t+1<nt){
            if constexpr (VM==4)      asm volatile("s_waitcnt vmcnt(4)" ::: "memory");
            else if constexpr (VM==6) asm volatile("s_waitcnt vmcnt(6)" ::: "memory");
            else if constexpr (VM==8) asm volatile("s_waitcnt vmcnt(8)" ::: "memory");
            else                      asm volatile("s_waitcnt vmcnt(0)" ::: "memory");
        } else {
            asm volatile("s_waitcnt vmcnt(0)" ::: "memory");
        }
        __builtin_amdgcn_s_barrier();
        __builtin_amdgcn_sched_barrier(0);
#pragma unroll
        for (int ks=0; ks<2; ++ks){
            bf16x8 af[MR], bv[NR];
            const int ch = (((ks*4+fq) ^ (fr&7))<<3);
#pragma unroll
            for (int j=0;j<MR;++j)
                af[j] = *(const bf16x8*)&bufA[(wm*(MR*16) + j*16 + fr)*64 + ch];
#pragma unroll
            for (int j=0;j<NR;++j)
                bv[j] = *(const bf16x8*)&bufB[(wn*(NR*16) + j*16 + fr)*64 + ch];
            __builtin_amdgcn_s_setprio(1);
#pragma unroll
            for (int mi=0;mi<MR;++mi)
#pragma unroll
            for (int ni=0;ni<NR;++ni)
                acc[mi][ni] = __builtin_amdgcn_mfma_f32_16x16x32_bf16(
                    af[mi], bv[ni], acc[mi][ni], 0,0,0);
            __builtin_amdgcn_s_setprio(0);
        }
        asm volatile("s_waitcnt lgkmcnt(0)" ::: "memory");
        __builtin_amdgcn_s_barrier();
        if (t+2<nt) STAGE(t+2, t&1);
    }

    float thr = 0.f;
    if constexpr (EPI==EPI_ADJ) thr = scal[sidx];

#pragma unroll
    for (int mi=0;mi<MR;++mi){
#pragma unroll
        for (int ni=0;ni<NR;++ni){
            const int col = bx*BN + wn*(NR*16) + ni*16 + fr;
#pragma unroll
            for (int r=0;r<4;++r){
                const int row = by*BM + wm*(MR*16) + mi*16 + fq*4 + r;
                const float v = acc[mi][ni][r];
                const long ci = (long)row*ldc + col;
                if constexpr (EPI==EPI_ADJ)       ((bf16*)Cout)[ci] = (bf16)sigm_f(10.f*(v - thr));
                else if constexpr (EPI==EPI_BF16) ((bf16*)Cout)[ci] = (bf16)v;
                else if constexpr (EPI==EPI_GELU_BIAS) ((bf16*)Cout)[ci] = (bf16)gelu_f(v + bias[col]);
                else if constexpr (EPI==EPI_BIAS_F32)  ((float*)Cout)[ci] = v + bias[col];
                else if constexpr (EPI==EPI_F32)       ((float*)Cout)[ci] = v;
                else if constexpr (EPI==EPI_XUPD){
                    const float u = 0.2f*(v + bias[col]);
                    xu0[ci] += u;  xu1[ci] += u;
                }
                else if constexpr (EPI==EPI_XUPDB){
                    const float u = 0.2f*(v + bias[col]);
                    const float n0 = xu0[ci] + u, n1 = xu1[ci] + u;
                    xu0[ci] = n0;  xu1[ci] = n1;
                    xbp[ci] = (bf16)n0;
                    xbp[ci + (long)2048*1024] = (bf16)n1;
                }
                else if constexpr (EPI==EPI_XUPDT){
                    const float u = 0.2f*(v + bias[col]);
                    const float n0 = xu0[ci] + u, n1 = xu1[ci] + u;
                    xu0[ci] = n0;  xu1[ci] = n1;
                    ((bf16*)Cout)[(long)row*2048 + col] = (bf16)n0;  // comb half
                    xbp[(long)col*2048 + row] = (bf16)n0;            // x0T
                }
            }
        }
    }
}

// ---------------------------------------------------------------------------
// 8-phase head GEMM (r14-verified): 256x256, quadrant phases, phase-aligned
// A staging units, vmcnt(6), full fencing, plain M-inner (fetch-optimal).
// ---------------------------------------------------------------------------
template<int EPI>
__global__ __launch_bounds__(512, 2)
void gemm8(const bf16* __restrict__ A, const bf16* __restrict__ B,
           int M, int N, int K, void* __restrict__ Cout, int ldc,
           const float* __restrict__ bias)
{
    __shared__ bf16 sm[65536];
    const int nbm = M>>8;
    const int wg = blockIdx.x;
    const int by = wg % nbm, bx = wg / nbm;
    const int tid = threadIdx.x, lane = tid&63, wid = tid>>6;
    const int wm = wid>>2, wn = wid&3;
    const int fr = lane&15, fq = lane>>4;

    const bf16* Ag = A + (long)(by*256 + (tid>>3))*K + (((tid&7) ^ ((tid>>3)&7))<<3);
    const bf16* Bg = B + (long)(bx*256 + (tid>>3))*K + (((tid&7) ^ ((tid>>3)&7))<<3);

    auto SA = [&](int tt, int h){
        bf16* d = sm + (tt&1)*32768 + wid*512;
        const long ko = (long)tt*64;
        gload16(Ag + (long)(h*64)*K + ko,       d + h*4096);
        gload16(Ag + (long)(128+h*64)*K + ko,   d + 8192 + h*4096);
    };
    auto SB = [&](int tt, int h){
        bf16* d = sm + (tt&1)*32768 + 16384 + wid*512;
        const long ko = (long)tt*64;
#pragma unroll
        for (int g=0; g<2; ++g)
            gload16(Bg + (long)(h*2+g)*64*K + ko, d + (h*2+g)*4096);
    };

    f32x4 acc[8][4] = {};
    bf16x8 aCur[8], b0[4], b1[4];
    const int nt = K >> 6;

    SA(0,0); SB(0,0); SA(0,1); SB(0,1);
    SA(1,0); SB(1,0); SA(1,1);
    SCHED_FENCE();

    for (int t=0; t<nt; ++t){
        const bf16* bufA = sm + (t&1)*32768;
        const bf16* bufB = bufA + 16384;

        auto LDA = [&](int mh){
#pragma unroll
            for (int ks=0;ks<2;++ks){
                const int ch = (((ks*4+fq) ^ (fr&7))<<3);
#pragma unroll
                for (int j=0;j<4;++j)
                    aCur[ks*4+j] = *(const bf16x8*)&bufA[(wm*128 + mh*64 + j*16 + fr)*64 + ch];
            }
        };
        auto LDB = [&](int nh, bf16x8* dst){
#pragma unroll
            for (int ks=0;ks<2;++ks){
                const int ch = (((ks*4+fq) ^ (fr&7))<<3);
#pragma unroll
                for (int j=0;j<2;++j)
                    dst[ks*2+j] = *(const bf16x8*)&bufB[(wn*64 + nh*32 + j*16 + fr)*64 + ch];
            }
        };
        auto QMFMA = [&](int mh, int nh, bf16x8* bArr){
            __builtin_amdgcn_s_setprio(1);
#pragma unroll
            for (int ks=0;ks<2;++ks)
#pragma unroll
            for (int j=0;j<4;++j)
#pragma unroll
            for (int jj=0;jj<2;++jj)
                acc[mh*4+j][nh*2+jj] = __builtin_amdgcn_mfma_f32_16x16x32_bf16(
                    aCur[ks*4+j], bArr[ks*2+jj], acc[mh*4+j][nh*2+jj], 0,0,0);
            __builtin_amdgcn_s_setprio(0);
            SCHED_FENCE();
        };

        // ---- phase 1: Q(0,0) ----
        if (t+1<nt) asm volatile("s_waitcnt vmcnt(6)" ::: "memory");
        else        asm volatile("s_waitcnt vmcnt(0)" ::: "memory");
        __builtin_amdgcn_s_barrier();
        SCHED_FENCE();
        if (t+1<nt) SB(t+1,1);
        SCHED_FENCE();
        LDA(0); LDB(0, b0);
        asm volatile("s_waitcnt lgkmcnt(0)" ::: "memory");
        SCHED_FENCE();
        QMFMA(0,0,b0);
        // ---- phase 2: Q(0,1) ----
        __builtin_amdgcn_s_barrier();
        SCHED_FENCE();
        if (t+2<nt) SA(t+2,0);
        SCHED_FENCE();
        LDB(1, b1);
        asm volatile("s_waitcnt lgkmcnt(0)" ::: "memory");
        SCHED_FENCE();
        QMFMA(0,1,b1);
        // ---- phase 3: Q(1,1) ----
        __builtin_amdgcn_s_barrier();
        SCHED_FENCE();
        if (t+2<nt) SB(t+2,0);
        SCHED_FENCE();
        LDA(1);
        asm volatile("s_waitcnt lgkmcnt(0)" ::: "memory");
        SCHED_FENCE();
        QMFMA(1,1,b1);
        // ---- phase 4: Q(1,0) ----
        __builtin_amdgcn_s_barrier();
        SCHED_FENCE();
        if (t+2<nt) SA(t+2,1);
        SCHED_FENCE();
        QMFMA(1,0,b0);
    }

#pragma unroll
    for (int mi=0;mi<8;++mi){
#pragma unroll
        for (int ni=0;ni<4;++ni){
            const int col = bx*256 + wn*64 + ni*16 + fr;
#pragma unroll
            for (int r=0;r<4;++r){
                const int row = by*256 + wm*128 + mi*16 + fq*4 + r;
                const float v = acc[mi][ni][r];
                const long ci = (long)row*ldc + col;
                if constexpr (EPI==EPI_F32)            ((float*)Cout)[ci] = v;
                else if constexpr (EPI==EPI_BIAS_F32)  ((float*)Cout)[ci] = v + bias[col];
                else                                   ((bf16*)Cout)[ci] = (bf16)v;
            }
        }
    }
}

// ---------------------------------------------------------------------------
// small kernels
// ---------------------------------------------------------------------------
__global__ void prep_kernel(const float* __restrict__ cs,
                            const float* __restrict__ W1, const float* __restrict__ b1,
                            const float* __restrict__ W2, const float* __restrict__ b2,
                            float* __restrict__ thrs)
{
    __shared__ float cp[1024];
    __shared__ float part[8][32];
    __shared__ float h[32];
    const int tid = threadIdx.x;
    for (int j = tid; j < 1024; j += 256){
        float s = 0.f;
#pragma unroll
        for (int r = 0; r < 8; r++) s += cs[r*1024 + j];
        cp[j] = s * 0.125f;
    }
    __syncthreads();
    const int t = tid & 31, g = tid >> 5;
    float p = 0.f;
    for (int j = g*128; j < g*128+128; j++) p += cp[j] * W1[j*32 + t];
    part[g][t] = p;
    __syncthreads();
    if (tid < 32){
        float s = b1[tid];
#pragma unroll
        for (int q=0;q<8;q++) s += part[q][tid];
        h[tid] = gelu_f(s);
    }
    __syncthreads();
    if (tid < 4){
        float z = b2[tid];
        for (int k=0;k<32;k++) z += h[k]*W2[k*4 + tid];
        thrs[tid] = sigm_f(z);
    }
    if (tid == 4) thrs[4] = 0.5f;   // betti threshold
}

__global__ void embed_kernel(const int* __restrict__ tok, const float* __restrict__ emb,
                             const float* __restrict__ pos, float* __restrict__ x)
{
    const long i = (long)blockIdx.x*256 + threadIdx.x;
    const int  d4 = i & 255;
    const long bt = i >> 8;
    const int  t  = (int)(bt & 2047);
    const int  token = tok[bt];
    f32x4 e = *(const f32x4*)(emb + (long)token*1024 + d4*4);
    f32x4 p = *(const f32x4*)(pos + (long)t*1024 + d4*4);
    *(f32x4*)(x + i*4) = e + p;
}

// batched f32->bf16 transpose: nb slices of [R][C] -> [C][R]
__global__ void transpose_f2b(const float* __restrict__ in, int ldin, long istr,
                              bf16* __restrict__ out, int ldout, long ostr,
                              int R, int C)
{
    __shared__ float tile[32][33];
    const int nbx = C >> 5, nby = R >> 5;
    const int per = nbx*nby;
    const int l  = blockIdx.x / per;
    const int rm = blockIdx.x % per;
    const int bx = rm % nbx, by = rm / nbx;
    const float* inl = in + (long)l*istr;
    bf16* outl = out + (long)l*ostr;
    const int tx = threadIdx.x & 31, ty = threadIdx.x >> 5;
#pragma unroll
    for (int i=0;i<32;i+=8)
        tile[ty+i][tx] = inl[(long)(by*32+ty+i)*ldin + bx*32+tx];
    __syncthreads();
#pragma unroll
    for (int i=0;i<32;i+=8)
        outl[(long)(bx*32+ty+i)*ldout + by*32+tx] = (bf16)tile[tx][ty+i];
}

__global__ void rownorm_kernel(const float* __restrict__ x, bf16* __restrict__ xn,
                               bf16* __restrict__ x0b, int ld0)
{
    const long t = blockIdx.x; const int tid = threadIdx.x;
    f32x4 v = *(const f32x4*)(x + t*1024 + tid*4);
    float s = v.x*v.x + v.y*v.y + v.z*v.z + v.w*v.w;
#pragma unroll
    for (int o=32;o>0;o>>=1) s += __shfl_down(s, o);
    __shared__ float red[4];
    if ((tid&63)==0) red[tid>>6] = s;
    __syncthreads();
    const float tot = red[0]+red[1]+red[2]+red[3];
    const float inv = 1.0f / fmaxf(sqrtf(tot), 1e-12f);
    bf16x4 a;
    a[0]=(bf16)(v.x*inv); a[1]=(bf16)(v.y*inv); a[2]=(bf16)(v.z*inv); a[3]=(bf16)(v.w*inv);
    *(bf16x4*)(xn + t*1024 + tid*4) = a;
    if (x0b){
        bf16x4 b;
        b[0]=(bf16)v.x; b[1]=(bf16)v.y; b[2]=(bf16)v.z; b[3]=(bf16)v.w;
        *(bf16x4*)(x0b + t*ld0 + tid*4) = b;
    }
}

__global__ void degree_kernel(const bf16* __restrict__ adj, float* __restrict__ deg)
{
    const long t = blockIdx.x; const int tid = threadIdx.x;
    bf16x8 v = *(const bf16x8*)(adj + t*2048 + tid*8);
    float s = 0.f;
#pragma unroll
    for (int j=0;j<8;j++) s += (float)v[j];
#pragma unroll
    for (int o=32;o>0;o>>=1) s += __shfl_down(s, o);
    __shared__ float red[4];
    if ((tid&63)==0) red[tid>>6] = s;
    __syncthreads();
    if (tid==0) deg[t] = red[0]+red[1]+red[2]+red[3];
}

__global__ void betti_kernel(const float* __restrict__ deg, float* __restrict__ betti)
{
    const int tid = threadIdx.x;
    float s = 0.f, c = 0.f;
#pragma unroll
    for (int i=0;i<8;i++){
        const float d = deg[tid*8 + i];
        s += d;  c += (d < 0.5f) ? 1.f : 0.f;
    }
#pragma unroll
    for (int o=32;o>0;o>>=1){ s += __shfl_down(s,o); c += __shfl_down(c,o); }
    __shared__ float ss[4], cc[4];
    if ((tid&63)==0){ ss[tid>>6]=s; cc[tid>>6]=c; }
    __syncthreads();
    if (tid==0){
        const float S = ss[0]+ss[1]+ss[2]+ss[3];
        const float C = cc[0]+cc[1]+cc[2]+cc[3];
        const float ne = 0.5f*S;
        const float b1 = ne - 2048.f + C + 1.f;
        betti[0] = C;
        betti[1] = b1 > 0.f ? b1 : 0.f;
    }
}

__global__ void b1eff_kernel(const float* __restrict__ ib1, const float* __restrict__ iW1,
                             const float* __restrict__ betti, float* __restrict__ out)
{
    const int j = blockIdx.x*256 + threadIdx.x;
    out[j] = ib1[j] + betti[0]*iW1[(long)1024*2048 + j] + betti[1]*iW1[(long)1025*2048 + j];
}

__global__ void ln_kernel(const float* __restrict__ y, const float* __restrict__ g,
                          const float* __restrict__ b, bf16* __restrict__ out)
{
    const long t = blockIdx.x; const int tid = threadIdx.x;
    f32x4 v = *(const f32x4*)(y + t*1024 + tid*4);
    float s  = v.x+v.y+v.z+v.w;
    float s2 = v.x*v.x+v.y*v.y+v.z*v.z+v.w*v.w;
#pragma unroll
    for (int o=32;o>0;o>>=1){ s += __shfl_down(s,o); s2 += __shfl_down(s2,o); }
    __shared__ float ss[4], qq[4];
    if ((tid&63)==0){ ss[tid>>6]=s; qq[tid>>6]=s2; }
    __syncthreads();
    const float S = ss[0]+ss[1]+ss[2]+ss[3], Q = qq[0]+qq[1]+qq[2]+qq[3];
    const float mu  = S * (1.f/1024.f);
    const float var = Q * (1.f/1024.f) - mu*mu;
    const float inv = rsqrtf(var + 1e-5f);
    f32x4 gv = *(const f32x4*)(g + tid*4);
    f32x4 bv = *(const f32x4*)(b + tid*4);
    bf16x4 o;
    o[0] = (bf16)((v.x - mu)*inv*gv.x + bv.x);
    o[1] = (bf16)((v.y - mu)*inv*gv.y + bv.y);
    o[2] = (bf16)((v.z - mu)*inv*gv.z + bv.z);
    o[3] = (bf16)((v.w - mu)*inv*gv.w + bv.w);
    *(bf16x4*)(out + t*1024 + tid*4) = o;
}

// ---------------------------------------------------------------------------
extern "C" void kernel_launch(void* const* d_in, const int* in_sizes, int n_in,
                              void* d_out, int out_size, void* d_ws, size_t ws_size,
                              hipStream_t stream)
{
    const int*   tokens = (const int*)  d_in[0];
    const float* cstate = (const float*)d_in[1];
    const float* embedW = (const float*)d_in[2];
    const float* posW   = (const float*)d_in[3];
    const float* thrW1  = (const float*)d_in[8];
    const float* thrb1  = (const float*)d_in[9];
    const float* thrW2  = (const float*)d_in[10];
    const float* thrb2  = (const float*)d_in[11];
    const float* simpW1 = (const float*)d_in[12];
    const float* simpb1 = (const float*)d_in[13];
    const float* simpW2 = (const float*)d_in[14];
    const float* simpb2 = (const float*)d_in[15];
    const float* intW1  = (const float*)d_in[16];
    const float* intb1  = (const float*)d_in[17];
    const float* intW2  = (const float*)d_in[18];
    const float* intb2  = (const float*)d_in[19];
    const float* lng    = (const float*)d_in[20];
    const float* lnb    = (const float*)d_in[21];
    const float* headW  = (const float*)d_in[22];
    float* out = (float*)d_out;

    size_t off = 0;
    auto carve = [&](size_t bytes) -> void* {
        void* p = (char*)d_ws + off;
        off += (bytes + 255) & ~(size_t)255;
        return p;
    };
    float* x_f32   = (float*)carve(16777216);
    bf16*  xn      = (bf16*) carve(4194304);
    bf16*  x0T     = (bf16*) carve(4194304);
    bf16*  comb    = (bf16*) carve(8388608);
    bf16*  adj     = (bf16*) carve(8388608);
    bf16*  h1      = (bf16*) carve(4194304);
    bf16*  xb      = (bf16*) carve(8388608);
    bf16*  w1T     = (bf16*) carve(16777216);
    bf16*  w2T     = (bf16*) carve(8388608);
    bf16*  i1T     = (bf16*) carve(4194304);
    bf16*  i2T     = (bf16*) carve(4194304);
    bf16*  hT      = (bf16*) carve(65536000);
    float* degree  = (float*)carve(8192);
    float* b1eff   = (float*)carve(8192);
    float* thrs    = (float*)carve(64);
    float* betti   = (float*)carve(64);
    bf16*  h2  = comb;
    float* yv  = x_f32;
    bf16*  xln = xn;

    const dim3 blk(256);
    const dim3 blk512(512);

    prep_kernel<<<1, blk, 0, stream>>>(cstate, thrW1, thrb1, thrW2, thrb2, thrs);
    embed_kernel<<<4096, blk, 0, stream>>>(tokens, embedW, posW, x_f32);

    // weight transposes (batched): w1T x4, w2T x4, then i1T, i2T, hT
    transpose_f2b<<<4*(1024/32)*(2048/32), blk, 0, stream>>>(
        simpW1, 1024, (long)2048*1024, w1T, 2048, (long)1024*2048, 2048, 1024);
    transpose_f2b<<<4*(1024/32)*(1024/32), blk, 0, stream>>>(
        simpW2, 1024, (long)1024*1024, w2T, 1024, (long)1024*1024, 1024, 1024);
    transpose_f2b<<<(2048/32)*(1024/32), blk, 0, stream>>>(
        intW1, 2048, 0, i1T, 1024, 0, 1024, 2048);
    transpose_f2b<<<(1024/32)*(2048/32), blk, 0, stream>>>(
        intW2, 1024, 0, i2T, 2048, 0, 2048, 1024);
    transpose_f2b<<<(32000/32)*(1024/32), blk, 0, stream>>>(
        headW, 32000, 0, hT, 1024, 0, 1024, 32000);

    for (int l=0;l<4;l++){
        if (l == 0){
            rownorm_kernel<<<2048, blk, 0, stream>>>(x_f32, xn, comb, 2048);
            transpose_f2b<<<(1024/32)*(2048/32), blk, 0, stream>>>(
                x_f32, 1024, 0, x0T, 2048, 0, 2048, 1024);
        } else {
            // comb-half and x0T were written by the previous level's XUPDT
            rownorm_kernel<<<2048, blk, 0, stream>>>(x_f32, xn, nullptr, 0);
        }
        gemm_p<128,128,2,2,2,EPI_ADJ><<<16*16, blk, 0, stream>>>(
            xn, xn, 2048, 2048, 1024, adj, 2048, nullptr, thrs, l, nullptr, nullptr, nullptr);
        gemm_p<64,64,2,2,4,EPI_BF16><<<32*16, blk, 0, stream>>>(
            adj, x0T, 2048, 1024, 2048, comb + 1024, 2048, nullptr, nullptr, 0, nullptr, nullptr, nullptr);
        gemm_p<64,64,2,2,4,EPI_GELU_BIAS><<<32*16, blk, 0, stream>>>(
            comb, w1T + (long)l*1024*2048, 2048, 1024, 2048, h1, 1024,
            simpb1 + l*1024, nullptr, 0, nullptr, nullptr, nullptr);
        if (l < 3)
            gemm_p<64,64,2,2,4,EPI_XUPDT><<<32*16, blk, 0, stream>>>(
                h1, w2T + (long)l*1024*1024, 2048, 1024, 1024, comb, 1024,
                simpb2 + l*1024, nullptr, 0, x_f32, x_f32 + (long)2048*1024, x0T);
        else
            gemm_p<64,64,2,2,4,EPI_XUPDB><<<32*16, blk, 0, stream>>>(
                h1, w2T + (long)l*1024*1024, 2048, 1024, 1024, nullptr, 1024,
                simpb2 + l*1024, nullptr, 0, x_f32, x_f32 + (long)2048*1024, xb);
    }

    rownorm_kernel<<<2048, blk, 0, stream>>>(x_f32, xn, nullptr, 0);
    gemm_p<128,128,2,2,2,EPI_ADJ><<<16*16, blk, 0, stream>>>(
        xn, xn, 2048, 2048, 1024, adj, 2048, nullptr, thrs, 4, nullptr, nullptr, nullptr);
    degree_kernel<<<2048, blk, 0, stream>>>(adj, degree);
    betti_kernel<<<1, blk, 0, stream>>>(degree, betti);
    b1eff_kernel<<<8, blk, 0, stream>>>(intb1, intW1, betti, b1eff);

    gemm_p<128,128,2,2,2,EPI_GELU_BIAS><<<32*16, blk, 0, stream>>>(
        xb, i1T, 4096, 2048, 1024, h2, 2048, b1eff, nullptr, 0, nullptr, nullptr, nullptr);
    gemm_p<64,128,2,2,3,EPI_BIAS_F32><<<64*8, blk, 0, stream>>>(
        h2, i2T, 4096, 1024, 2048, yv, 1024, intb2, nullptr, 0, nullptr, nullptr, nullptr);
    ln_kernel<<<4096, blk, 0, stream>>>(yv, lng, lnb, xln);
    gemm8<EPI_F32><<<16*125, blk512, 0, stream>>>(
        xln, hT, 4096, 32000, 1024, out, 32000, nullptr);
}

// Round 16
// 802.594 us; speedup vs baseline: 1.0883x; 1.0123x over previous
//
#include <hip/hip_runtime.h>

typedef __bf16 bf16;
using bf16x8 = __attribute__((ext_vector_type(8))) __bf16;
using bf16x4 = __attribute__((ext_vector_type(4))) __bf16;
using f32x4  = __attribute__((ext_vector_type(4))) float;

#define DEV __device__ __forceinline__
#define SCHED_FENCE() __builtin_amdgcn_sched_barrier(0)

DEV float gelu_f(float x){ return 0.5f*x*(1.0f+erff(x*0.7071067811865475f)); }
DEV float sigm_f(float x){ return 1.0f/(1.0f+expf(-x)); }

DEV void gload16(const bf16* g, bf16* l){
    __builtin_amdgcn_global_load_lds(
        (const __attribute__((address_space(1))) void*)g,
        (__attribute__((address_space(3))) void*)l, 16, 0, 0);
}

enum { EPI_ADJ=0, EPI_BF16=1, EPI_GELU_BIAS=2, EPI_XUPD=3, EPI_BIAS_F32=4, EPI_F32=5,
       EPI_XUPDB=6, EPI_XUPDT=7 };

// ---------------------------------------------------------------------------
// r5-proven GEMM: BK=64, 2 LDS buffers, counted vmcnt, both-sides swizzle.
// ---------------------------------------------------------------------------
template<int BM,int BN,int WM,int WN,int MINW,int EPI>
__global__ __launch_bounds__(WM*WN*64, MINW)
void gemm_p(const bf16* __restrict__ A, const bf16* __restrict__ B,
            int M, int N, int K, void* __restrict__ Cout, int ldc,
            const float* __restrict__ bias, const float* __restrict__ scal, int sidx,
            float* __restrict__ xu0, float* __restrict__ xu1, bf16* __restrict__ xbp)
{
    constexpr int THREADS = WM*WN*64;
    constexpr int MR = BM/WM/16, NR = BN/WN/16;
    constexpr int ATILE = BM*64, BTILE = BN*64;
    constexpr int RR = THREADS/8;
    constexpr int VM = (BM+BN)/RR;
    __shared__ bf16 sm[2*(ATILE+BTILE)];

    const int nbm = M/BM, nbn = N/BN;
    const int nwg = nbm*nbn;
    int wg = blockIdx.x;
    wg = (wg&7)*(nwg>>3) + (wg>>3);
    const int by = wg % nbm, bx = wg / nbm;
    const int tid = threadIdx.x, lane = tid&63, wid = tid>>6;
    const int wm = wid / WN, wn = wid % WN;
    const int fr = lane&15, fq = lane>>4;

    const bf16* Ab = A + (long)(by*BM + (tid>>3))*K + (((tid&7) ^ ((tid>>3)&7))<<3);
    const bf16* Bb = B + (long)(bx*BN + (tid>>3))*K + (((tid&7) ^ ((tid>>3)&7))<<3);

    auto STAGE = [&](int tt, int cb){
        bf16* d = sm + cb*(ATILE+BTILE) + wid*512;
        const long ko = (long)tt*64;
#pragma unroll
        for (int g=0; g<BM/RR; ++g)
            gload16(Ab + (long)g*RR*K + ko, d + g*RR*64);
#pragma unroll
        for (int g=0; g<BN/RR; ++g)
            gload16(Bb + (long)g*RR*K + ko, d + ATILE + g*RR*64);
    };

    f32x4 acc[MR][NR] = {};
    const int nt = K >> 6;

    STAGE(0,0);
    STAGE(1,1);

    for (int t=0; t<nt; ++t){
        const bf16* bufA = sm + (t&1)*(ATILE+BTILE);
        const bf16* bufB = bufA + ATILE;
        if (t+1<nt){
            if constexpr (VM==4)      asm volatile("s_waitcnt vmcnt(4)" ::: "memory");
            else if constexpr (VM==6) asm volatile("s_waitcnt vmcnt(6)" ::: "memory");
            else if constexpr (VM==8) asm volatile("s_waitcnt vmcnt(8)" ::: "memory");
            else                      asm volatile("s_waitcnt vmcnt(0)" ::: "memory");
        } else {
            asm volatile("s_waitcnt vmcnt(0)" ::: "memory");
        }
        __builtin_amdgcn_s_barrier();
        __builtin_amdgcn_sched_barrier(0);
#pragma unroll
        for (int ks=0; ks<2; ++ks){
            bf16x8 af[MR], bv[NR];
            const int ch = (((ks*4+fq) ^ (fr&7))<<3);
#pragma unroll
            for (int j=0;j<MR;++j)
                af[j] = *(const bf16x8*)&bufA[(wm*(MR*16) + j*16 + fr)*64 + ch];
#pragma unroll
            for (int j=0;j<NR;++j)
                bv[j] = *(const bf16x8*)&bufB[(wn*(NR*16) + j*16 + fr)*64 + ch];
            __builtin_amdgcn_s_setprio(1);
#pragma unroll
            for (int mi=0;mi<MR;++mi)
#pragma unroll
            for (int ni=0;ni<NR;++ni)
                acc[mi][ni] = __builtin_amdgcn_mfma_f32_16x16x32_bf16(
                    af[mi], bv[ni], acc[mi][ni], 0,0,0);
            __builtin_amdgcn_s_setprio(0);
        }
        asm volatile("s_waitcnt lgkmcnt(0)" ::: "memory");
        __builtin_amdgcn_s_barrier();
        if (t+2<nt) STAGE(t+2, t&1);
    }

    float thr = 0.f;
    if constexpr (EPI==EPI_ADJ) thr = scal[sidx];

#pragma unroll
    for (int mi=0;mi<MR;++mi){
#pragma unroll
        for (int ni=0;ni<NR;++ni){
            const int col = bx*BN + wn*(NR*16) + ni*16 + fr;
#pragma unroll
            for (int r=0;r<4;++r){
                const int row = by*BM + wm*(MR*16) + mi*16 + fq*4 + r;
                const float v = acc[mi][ni][r];
                const long ci = (long)row*ldc + col;
                if constexpr (EPI==EPI_ADJ)       ((bf16*)Cout)[ci] = (bf16)sigm_f(10.f*(v - thr));
                else if constexpr (EPI==EPI_BF16) ((bf16*)Cout)[ci] = (bf16)v;
                else if constexpr (EPI==EPI_GELU_BIAS) ((bf16*)Cout)[ci] = (bf16)gelu_f(v + bias[col]);
                else if constexpr (EPI==EPI_BIAS_F32)  ((float*)Cout)[ci] = v + bias[col];
                else if constexpr (EPI==EPI_F32)       ((float*)Cout)[ci] = v;
                else if constexpr (EPI==EPI_XUPD){
                    const float u = 0.2f*(v + bias[col]);
                    xu0[ci] += u;  xu1[ci] += u;
                }
                else if constexpr (EPI==EPI_XUPDB){
                    const float u = 0.2f*(v + bias[col]);
                    const float n0 = xu0[ci] + u, n1 = xu1[ci] + u;
                    xu0[ci] = n0;  xu1[ci] = n1;
                    xbp[ci] = (bf16)n0;
                    xbp[ci + (long)2048*1024] = (bf16)n1;
                }
                else if constexpr (EPI==EPI_XUPDT){
                    const float u = 0.2f*(v + bias[col]);
                    const float n0 = xu0[ci] + u, n1 = xu1[ci] + u;
                    xu0[ci] = n0;  xu1[ci] = n1;
                    ((bf16*)Cout)[(long)row*2048 + col] = (bf16)n0;  // comb half
                    xbp[(long)col*2048 + row] = (bf16)n0;            // x0T
                }
            }
        }
    }
}

// ---------------------------------------------------------------------------
// 8-phase head GEMM (r14-verified): 256x256, quadrant phases, phase-aligned
// A staging units, vmcnt(6), full fencing, plain M-inner (fetch-optimal).
// FROZEN: MfmaUtil 37% = exact FLOP floor when busy; staging volume fixes a
// ~54% util ceiling for this tile; bigger tiles / 2 blocks/CU are VGPR/LDS-
// impossible. Two correctness failures on schedule edits -> do not touch.
// ---------------------------------------------------------------------------
template<int EPI>
__global__ __launch_bounds__(512, 2)
void gemm8(const bf16* __restrict__ A, const bf16* __restrict__ B,
           int M, int N, int K, void* __restrict__ Cout, int ldc,
           const float* __restrict__ bias)
{
    __shared__ bf16 sm[65536];
    const int nbm = M>>8;
    const int wg = blockIdx.x;
    const int by = wg % nbm, bx = wg / nbm;
    const int tid = threadIdx.x, lane = tid&63, wid = tid>>6;
    const int wm = wid>>2, wn = wid&3;
    const int fr = lane&15, fq = lane>>4;

    const bf16* Ag = A + (long)(by*256 + (tid>>3))*K + (((tid&7) ^ ((tid>>3)&7))<<3);
    const bf16* Bg = B + (long)(bx*256 + (tid>>3))*K + (((tid&7) ^ ((tid>>3)&7))<<3);

    auto SA = [&](int tt, int h){
        bf16* d = sm + (tt&1)*32768 + wid*512;
        const long ko = (long)tt*64;
        gload16(Ag + (long)(h*64)*K + ko,       d + h*4096);
        gload16(Ag + (long)(128+h*64)*K + ko,   d + 8192 + h*4096);
    };
    auto SB = [&](int tt, int h){
        bf16* d = sm + (tt&1)*32768 + 16384 + wid*512;
        const long ko = (long)tt*64;
#pragma unroll
        for (int g=0; g<2; ++g)
            gload16(Bg + (long)(h*2+g)*64*K + ko, d + (h*2+g)*4096);
    };

    f32x4 acc[8][4] = {};
    bf16x8 aCur[8], b0[4], b1[4];
    const int nt = K >> 6;

    SA(0,0); SB(0,0); SA(0,1); SB(0,1);
    SA(1,0); SB(1,0); SA(1,1);
    SCHED_FENCE();

    for (int t=0; t<nt; ++t){
        const bf16* bufA = sm + (t&1)*32768;
        const bf16* bufB = bufA + 16384;

        auto LDA = [&](int mh){
#pragma unroll
            for (int ks=0;ks<2;++ks){
                const int ch = (((ks*4+fq) ^ (fr&7))<<3);
#pragma unroll
                for (int j=0;j<4;++j)
                    aCur[ks*4+j] = *(const bf16x8*)&bufA[(wm*128 + mh*64 + j*16 + fr)*64 + ch];
            }
        };
        auto LDB = [&](int nh, bf16x8* dst){
#pragma unroll
            for (int ks=0;ks<2;++ks){
                const int ch = (((ks*4+fq) ^ (fr&7))<<3);
#pragma unroll
                for (int j=0;j<2;++j)
                    dst[ks*2+j] = *(const bf16x8*)&bufB[(wn*64 + nh*32 + j*16 + fr)*64 + ch];
            }
        };
        auto QMFMA = [&](int mh, int nh, bf16x8* bArr){
            __builtin_amdgcn_s_setprio(1);
#pragma unroll
            for (int ks=0;ks<2;++ks)
#pragma unroll
            for (int j=0;j<4;++j)
#pragma unroll
            for (int jj=0;jj<2;++jj)
                acc[mh*4+j][nh*2+jj] = __builtin_amdgcn_mfma_f32_16x16x32_bf16(
                    aCur[ks*4+j], bArr[ks*2+jj], acc[mh*4+j][nh*2+jj], 0,0,0);
            __builtin_amdgcn_s_setprio(0);
            SCHED_FENCE();
        };

        // ---- phase 1: Q(0,0) ----
        if (t+1<nt) asm volatile("s_waitcnt vmcnt(6)" ::: "memory");
        else        asm volatile("s_waitcnt vmcnt(0)" ::: "memory");
        __builtin_amdgcn_s_barrier();
        SCHED_FENCE();
        if (t+1<nt) SB(t+1,1);
        SCHED_FENCE();
        LDA(0); LDB(0, b0);
        asm volatile("s_waitcnt lgkmcnt(0)" ::: "memory");
        SCHED_FENCE();
        QMFMA(0,0,b0);
        // ---- phase 2: Q(0,1) ----
        __builtin_amdgcn_s_barrier();
        SCHED_FENCE();
        if (t+2<nt) SA(t+2,0);
        SCHED_FENCE();
        LDB(1, b1);
        asm volatile("s_waitcnt lgkmcnt(0)" ::: "memory");
        SCHED_FENCE();
        QMFMA(0,1,b1);
        // ---- phase 3: Q(1,1) ----
        __builtin_amdgcn_s_barrier();
        SCHED_FENCE();
        if (t+2<nt) SB(t+2,0);
        SCHED_FENCE();
        LDA(1);
        asm volatile("s_waitcnt lgkmcnt(0)" ::: "memory");
        SCHED_FENCE();
        QMFMA(1,1,b1);
        // ---- phase 4: Q(1,0) ----
        __builtin_amdgcn_s_barrier();
        SCHED_FENCE();
        if (t+2<nt) SA(t+2,1);
        SCHED_FENCE();
        QMFMA(1,0,b0);
    }

#pragma unroll
    for (int mi=0;mi<8;++mi){
#pragma unroll
        for (int ni=0;ni<4;++ni){
            const int col = bx*256 + wn*64 + ni*16 + fr;
#pragma unroll
            for (int r=0;r<4;++r){
                const int row = by*256 + wm*128 + mi*16 + fq*4 + r;
                const float v = acc[mi][ni][r];
                const long ci = (long)row*ldc + col;
                if constexpr (EPI==EPI_F32)            ((float*)Cout)[ci] = v;
                else if constexpr (EPI==EPI_BIAS_F32)  ((float*)Cout)[ci] = v + bias[col];
                else                                   ((bf16*)Cout)[ci] = (bf16)v;
            }
        }
    }
}

// ---------------------------------------------------------------------------
// small kernels
// ---------------------------------------------------------------------------
__global__ void prep_kernel(const float* __restrict__ cs,
                            const float* __restrict__ W1, const float* __restrict__ b1,
                            const float* __restrict__ W2, const float* __restrict__ b2,
                            float* __restrict__ thrs)
{
    __shared__ float cp[1024];
    __shared__ float part[8][32];
    __shared__ float h[32];
    const int tid = threadIdx.x;
    for (int j = tid; j < 1024; j += 256){
        float s = 0.f;
#pragma unroll
        for (int r = 0; r < 8; r++) s += cs[r*1024 + j];
        cp[j] = s * 0.125f;
    }
    __syncthreads();
    const int t = tid & 31, g = tid >> 5;
    float p = 0.f;
    for (int j = g*128; j < g*128+128; j++) p += cp[j] * W1[j*32 + t];
    part[g][t] = p;
    __syncthreads();
    if (tid < 32){
        float s = b1[tid];
#pragma unroll
        for (int q=0;q<8;q++) s += part[q][tid];
        h[tid] = gelu_f(s);
    }
    __syncthreads();
    if (tid < 4){
        float z = b2[tid];
        for (int k=0;k<32;k++) z += h[k]*W2[k*4 + tid];
        thrs[tid] = sigm_f(z);
    }
    if (tid == 4) thrs[4] = 0.5f;   // betti threshold
}

__global__ void embed_kernel(const int* __restrict__ tok, const float* __restrict__ emb,
                             const float* __restrict__ pos, float* __restrict__ x)
{
    const long i = (long)blockIdx.x*256 + threadIdx.x;
    const int  d4 = i & 255;
    const long bt = i >> 8;
    const int  t  = (int)(bt & 2047);
    const int  token = tok[bt];
    f32x4 e = *(const f32x4*)(emb + (long)token*1024 + d4*4);
    f32x4 p = *(const f32x4*)(pos + (long)t*1024 + d4*4);
    *(f32x4*)(x + i*4) = e + p;
}

// batched f32->bf16 transpose: nb slices of [R][C] -> [C][R]
__global__ void transpose_f2b(const float* __restrict__ in, int ldin, long istr,
                              bf16* __restrict__ out, int ldout, long ostr,
                              int R, int C)
{
    __shared__ float tile[32][33];
    const int nbx = C >> 5, nby = R >> 5;
    const int per = nbx*nby;
    const int l  = blockIdx.x / per;
    const int rm = blockIdx.x % per;
    const int bx = rm % nbx, by = rm / nbx;
    const float* inl = in + (long)l*istr;
    bf16* outl = out + (long)l*ostr;
    const int tx = threadIdx.x & 31, ty = threadIdx.x >> 5;
#pragma unroll
    for (int i=0;i<32;i+=8)
        tile[ty+i][tx] = inl[(long)(by*32+ty+i)*ldin + bx*32+tx];
    __syncthreads();
#pragma unroll
    for (int i=0;i<32;i+=8)
        outl[(long)(bx*32+ty+i)*ldout + by*32+tx] = (bf16)tile[tx][ty+i];
}

__global__ void rownorm_kernel(const float* __restrict__ x, bf16* __restrict__ xn,
                               bf16* __restrict__ x0b, int ld0)
{
    const long t = blockIdx.x; const int tid = threadIdx.x;
    f32x4 v = *(const f32x4*)(x + t*1024 + tid*4);
    float s = v.x*v.x + v.y*v.y + v.z*v.z + v.w*v.w;
#pragma unroll
    for (int o=32;o>0;o>>=1) s += __shfl_down(s, o);
    __shared__ float red[4];
    if ((tid&63)==0) red[tid>>6] = s;
    __syncthreads();
    const float tot = red[0]+red[1]+red[2]+red[3];
    const float inv = 1.0f / fmaxf(sqrtf(tot), 1e-12f);
    bf16x4 a;
    a[0]=(bf16)(v.x*inv); a[1]=(bf16)(v.y*inv); a[2]=(bf16)(v.z*inv); a[3]=(bf16)(v.w*inv);
    *(bf16x4*)(xn + t*1024 + tid*4) = a;
    if (x0b){
        bf16x4 b;
        b[0]=(bf16)v.x; b[1]=(bf16)v.y; b[2]=(bf16)v.z; b[3]=(bf16)v.w;
        *(bf16x4*)(x0b + t*ld0 + tid*4) = b;
    }
}

__global__ void degree_kernel(const bf16* __restrict__ adj, float* __restrict__ deg)
{
    const long t = blockIdx.x; const int tid = threadIdx.x;
    bf16x8 v = *(const bf16x8*)(adj + t*2048 + tid*8);
    float s = 0.f;
#pragma unroll
    for (int j=0;j<8;j++) s += (float)v[j];
#pragma unroll
    for (int o=32;o>0;o>>=1) s += __shfl_down(s, o);
    __shared__ float red[4];
    if ((tid&63)==0) red[tid>>6] = s;
    __syncthreads();
    if (tid==0) deg[t] = red[0]+red[1]+red[2]+red[3];
}

__global__ void betti_kernel(const float* __restrict__ deg, float* __restrict__ betti)
{
    const int tid = threadIdx.x;
    float s = 0.f, c = 0.f;
#pragma unroll
    for (int i=0;i<8;i++){
        const float d = deg[tid*8 + i];
        s += d;  c += (d < 0.5f) ? 1.f : 0.f;
    }
#pragma unroll
    for (int o=32;o>0;o>>=1){ s += __shfl_down(s,o); c += __shfl_down(c,o); }
    __shared__ float ss[4], cc[4];
    if ((tid&63)==0){ ss[tid>>6]=s; cc[tid>>6]=c; }
    __syncthreads();
    if (tid==0){
        const float S = ss[0]+ss[1]+ss[2]+ss[3];
        const float C = cc[0]+cc[1]+cc[2]+cc[3];
        const float ne = 0.5f*S;
        const float b1 = ne - 2048.f + C + 1.f;
        betti[0] = C;
        betti[1] = b1 > 0.f ? b1 : 0.f;
    }
}

__global__ void b1eff_kernel(const float* __restrict__ ib1, const float* __restrict__ iW1,
                             const float* __restrict__ betti, float* __restrict__ out)
{
    const int j = blockIdx.x*256 + threadIdx.x;
    out[j] = ib1[j] + betti[0]*iW1[(long)1024*2048 + j] + betti[1]*iW1[(long)1025*2048 + j];
}

__global__ void ln_kernel(const float* __restrict__ y, const float* __restrict__ g,
                          const float* __restrict__ b, bf16* __restrict__ out)
{
    const long t = blockIdx.x; const int tid = threadIdx.x;
    f32x4 v = *(const f32x4*)(y + t*1024 + tid*4);
    float s  = v.x+v.y+v.z+v.w;
    float s2 = v.x*v.x+v.y*v.y+v.z*v.z+v.w*v.w;
#pragma unroll
    for (int o=32;o>0;o>>=1){ s += __shfl_down(s,o); s2 += __shfl_down(s2,o); }
    __shared__ float ss[4], qq[4];
    if ((tid&63)==0){ ss[tid>>6]=s; qq[tid>>6]=s2; }
    __syncthreads();
    const float S = ss[0]+ss[1]+ss[2]+ss[3], Q = qq[0]+qq[1]+qq[2]+qq[3];
    const float mu  = S * (1.f/1024.f);
    const float var = Q * (1.f/1024.f) - mu*mu;
    const float inv = rsqrtf(var + 1e-5f);
    f32x4 gv = *(const f32x4*)(g + tid*4);
    f32x4 bv = *(const f32x4*)(b + tid*4);
    bf16x4 o;
    o[0] = (bf16)((v.x - mu)*inv*gv.x + bv.x);
    o[1] = (bf16)((v.y - mu)*inv*gv.y + bv.y);
    o[2] = (bf16)((v.z - mu)*inv*gv.z + bv.z);
    o[3] = (bf16)((v.w - mu)*inv*gv.w + bv.w);
    *(bf16x4*)(out + t*1024 + tid*4) = o;
}

// ---------------------------------------------------------------------------
extern "C" void kernel_launch(void* const* d_in, const int* in_sizes, int n_in,
                              void* d_out, int out_size, void* d_ws, size_t ws_size,
                              hipStream_t stream)
{
    const int*   tokens = (const int*)  d_in[0];
    const float* cstate = (const float*)d_in[1];
    const float* embedW = (const float*)d_in[2];
    const float* posW   = (const float*)d_in[3];
    const float* thrW1  = (const float*)d_in[8];
    const float* thrb1  = (const float*)d_in[9];
    const float* thrW2  = (const float*)d_in[10];
    const float* thrb2  = (const float*)d_in[11];
    const float* simpW1 = (const float*)d_in[12];
    const float* simpb1 = (const float*)d_in[13];
    const float* simpW2 = (const float*)d_in[14];
    const float* simpb2 = (const float*)d_in[15];
    const float* intW1  = (const float*)d_in[16];
    const float* intb1  = (const float*)d_in[17];
    const float* intW2  = (const float*)d_in[18];
    const float* intb2  = (const float*)d_in[19];
    const float* lng    = (const float*)d_in[20];
    const float* lnb    = (const float*)d_in[21];
    const float* headW  = (const float*)d_in[22];
    float* out = (float*)d_out;

    size_t off = 0;
    auto carve = [&](size_t bytes) -> void* {
        void* p = (char*)d_ws + off;
        off += (bytes + 255) & ~(size_t)255;
        return p;
    };
    float* x_f32   = (float*)carve(16777216);
    bf16*  xn      = (bf16*) carve(4194304);
    bf16*  x0T     = (bf16*) carve(4194304);
    bf16*  comb    = (bf16*) carve(8388608);
    bf16*  adj     = (bf16*) carve(8388608);
    bf16*  h1      = (bf16*) carve(4194304);
    bf16*  xb      = (bf16*) carve(8388608);
    bf16*  w1T     = (bf16*) carve(16777216);
    bf16*  w2T     = (bf16*) carve(8388608);
    bf16*  i1T     = (bf16*) carve(4194304);
    bf16*  i2T     = (bf16*) carve(4194304);
    bf16*  hT      = (bf16*) carve(65536000);
    float* degree  = (float*)carve(8192);
    float* b1eff   = (float*)carve(8192);
    float* thrs    = (float*)carve(64);
    float* betti   = (float*)carve(64);
    bf16*  h2  = comb;
    float* yv  = x_f32;
    bf16*  xln = xn;

    const dim3 blk(256);
    const dim3 blk512(512);

    prep_kernel<<<1, blk, 0, stream>>>(cstate, thrW1, thrb1, thrW2, thrb2, thrs);
    embed_kernel<<<4096, blk, 0, stream>>>(tokens, embedW, posW, x_f32);

    // weight transposes (batched): w1T x4, w2T x4, then i1T, i2T, hT
    transpose_f2b<<<4*(1024/32)*(2048/32), blk, 0, stream>>>(
        simpW1, 1024, (long)2048*1024, w1T, 2048, (long)1024*2048, 2048, 1024);
    transpose_f2b<<<4*(1024/32)*(1024/32), blk, 0, stream>>>(
        simpW2, 1024, (long)1024*1024, w2T, 1024, (long)1024*1024, 1024, 1024);
    transpose_f2b<<<(2048/32)*(1024/32), blk, 0, stream>>>(
        intW1, 2048, 0, i1T, 1024, 0, 1024, 2048);
    transpose_f2b<<<(1024/32)*(2048/32), blk, 0, stream>>>(
        intW2, 1024, 0, i2T, 2048, 0, 2048, 1024);
    transpose_f2b<<<(32000/32)*(1024/32), blk, 0, stream>>>(
        headW, 32000, 0, hT, 1024, 0, 1024, 32000);

    for (int l=0;l<4;l++){
        if (l == 0){
            rownorm_kernel<<<2048, blk, 0, stream>>>(x_f32, xn, comb, 2048);
            transpose_f2b<<<(1024/32)*(2048/32), blk, 0, stream>>>(
                x_f32, 1024, 0, x0T, 2048, 0, 2048, 1024);
        } else {
            // comb-half and x0T were written by the previous level's XUPDT
            rownorm_kernel<<<2048, blk, 0, stream>>>(x_f32, xn, nullptr, 0);
        }
        gemm_p<64,128,2,2,3,EPI_ADJ><<<32*16, blk, 0, stream>>>(
            xn, xn, 2048, 2048, 1024, adj, 2048, nullptr, thrs, l, nullptr, nullptr, nullptr);
        gemm_p<64,64,2,2,4,EPI_BF16><<<32*16, blk, 0, stream>>>(
            adj, x0T, 2048, 1024, 2048, comb + 1024, 2048, nullptr, nullptr, 0, nullptr, nullptr, nullptr);
        gemm_p<64,64,2,2,4,EPI_GELU_BIAS><<<32*16, blk, 0, stream>>>(
            comb, w1T + (long)l*1024*2048, 2048, 1024, 2048, h1, 1024,
            simpb1 + l*1024, nullptr, 0, nullptr, nullptr, nullptr);
        if (l < 3)
            gemm_p<64,64,2,2,4,EPI_XUPDT><<<32*16, blk, 0, stream>>>(
                h1, w2T + (long)l*1024*1024, 2048, 1024, 1024, comb, 1024,
                simpb2 + l*1024, nullptr, 0, x_f32, x_f32 + (long)2048*1024, x0T);
        else
            gemm_p<64,64,2,2,4,EPI_XUPDB><<<32*16, blk, 0, stream>>>(
                h1, w2T + (long)l*1024*1024, 2048, 1024, 1024, nullptr, 1024,
                simpb2 + l*1024, nullptr, 0, x_f32, x_f32 + (long)2048*1024, xb);
    }

    rownorm_kernel<<<2048, blk, 0, stream>>>(x_f32, xn, nullptr, 0);
    gemm_p<64,128,2,2,3,EPI_ADJ><<<32*16, blk, 0, stream>>>(
        xn, xn, 2048, 2048, 1024, adj, 2048, nullptr, thrs, 4, nullptr, nullptr, nullptr);
    degree_kernel<<<2048, blk, 0, stream>>>(adj, degree);
    betti_kernel<<<1, blk, 0, stream>>>(degree, betti);
    b1eff_kernel<<<8, blk, 0, stream>>>(intb1, intW1, betti, b1eff);

    gemm_p<128,128,2,2,2,EPI_GELU_BIAS><<<32*16, blk, 0, stream>>>(
        xb, i1T, 4096, 2048, 1024, h2, 2048, b1eff, nullptr, 0, nullptr, nullptr, nullptr);
    gemm_p<64,128,2,2,3,EPI_BIAS_F32><<<64*8, blk, 0, stream>>>(
        h2, i2T, 4096, 1024, 2048, yv, 1024, intb2, nullptr, 0, nullptr, nullptr, nullptr);
    ln_kernel<<<4096, blk, 0, stream>>>(yv, lng, lnb, xln);
    gemm8<EPI_F32><<<16*125, blk512, 0, stream>>>(
        xln, hT, 4096, 32000, 1024, out, 32000, nullptr);
}

// Round 17
// 796.414 us; speedup vs baseline: 1.0968x; 1.0078x over previous
//
#include <hip/hip_runtime.h>

typedef __bf16 bf16;
using bf16x8 = __attribute__((ext_vector_type(8))) __bf16;
using bf16x4 = __attribute__((ext_vector_type(4))) __bf16;
using f32x4  = __attribute__((ext_vector_type(4))) float;

#define DEV __device__ __forceinline__
#define SCHED_FENCE() __builtin_amdgcn_sched_barrier(0)

DEV float gelu_f(float x){ return 0.5f*x*(1.0f+erff(x*0.7071067811865475f)); }
DEV float sigm_f(float x){ return 1.0f/(1.0f+expf(-x)); }

DEV void gload16(const bf16* g, bf16* l){
    __builtin_amdgcn_global_load_lds(
        (const __attribute__((address_space(1))) void*)g,
        (__attribute__((address_space(3))) void*)l, 16, 0, 0);
}

enum { EPI_ADJ=0, EPI_BF16=1, EPI_GELU_BIAS=2, EPI_XUPD=3, EPI_BIAS_F32=4, EPI_F32=5,
       EPI_XUPDB=6, EPI_XUPDT=7, EPI_DEG=8 };

// ---------------------------------------------------------------------------
// r5-proven GEMM: BK=64, 2 LDS buffers, counted vmcnt, both-sides swizzle.
// EPI_XUPDT: x0 += u, write next-level comb-half + x0T from registers.
// EPI_XUPDB: x0 += u; xb0 = x0, xb1 = x0 + delta (batch-1 reconstructed).
// EPI_DEG:   fused degree row-sums (sigma + shfl-reduce + atomicAdd), no C.
// ---------------------------------------------------------------------------
template<int BM,int BN,int WM,int WN,int MINW,int EPI>
__global__ __launch_bounds__(WM*WN*64, MINW)
void gemm_p(const bf16* __restrict__ A, const bf16* __restrict__ B,
            int M, int N, int K, void* __restrict__ Cout, int ldc,
            const float* __restrict__ bias, const float* __restrict__ scal, int sidx,
            float* __restrict__ xu0, float* __restrict__ xu1, bf16* __restrict__ xbp)
{
    constexpr int THREADS = WM*WN*64;
    constexpr int MR = BM/WM/16, NR = BN/WN/16;
    constexpr int ATILE = BM*64, BTILE = BN*64;
    constexpr int RR = THREADS/8;
    constexpr int VM = (BM+BN)/RR;
    __shared__ bf16 sm[2*(ATILE+BTILE)];

    const int nbm = M/BM, nbn = N/BN;
    const int nwg = nbm*nbn;
    int wg = blockIdx.x;
    wg = (wg&7)*(nwg>>3) + (wg>>3);
    const int by = wg % nbm, bx = wg / nbm;
    const int tid = threadIdx.x, lane = tid&63, wid = tid>>6;
    const int wm = wid / WN, wn = wid % WN;
    const int fr = lane&15, fq = lane>>4;

    const bf16* Ab = A + (long)(by*BM + (tid>>3))*K + (((tid&7) ^ ((tid>>3)&7))<<3);
    const bf16* Bb = B + (long)(bx*BN + (tid>>3))*K + (((tid&7) ^ ((tid>>3)&7))<<3);

    auto STAGE = [&](int tt, int cb){
        bf16* d = sm + cb*(ATILE+BTILE) + wid*512;
        const long ko = (long)tt*64;
#pragma unroll
        for (int g=0; g<BM/RR; ++g)
            gload16(Ab + (long)g*RR*K + ko, d + g*RR*64);
#pragma unroll
        for (int g=0; g<BN/RR; ++g)
            gload16(Bb + (long)g*RR*K + ko, d + ATILE + g*RR*64);
    };

    f32x4 acc[MR][NR] = {};
    const int nt = K >> 6;

    STAGE(0,0);
    STAGE(1,1);

    for (int t=0; t<nt; ++t){
        const bf16* bufA = sm + (t&1)*(ATILE+BTILE);
        const bf16* bufB = bufA + ATILE;
        if (t+1<nt){
            if constexpr (VM==4)      asm volatile("s_waitcnt vmcnt(4)" ::: "memory");
            else if constexpr (VM==6) asm volatile("s_waitcnt vmcnt(6)" ::: "memory");
            else if constexpr (VM==8) asm volatile("s_waitcnt vmcnt(8)" ::: "memory");
            else                      asm volatile("s_waitcnt vmcnt(0)" ::: "memory");
        } else {
            asm volatile("s_waitcnt vmcnt(0)" ::: "memory");
        }
        __builtin_amdgcn_s_barrier();
        __builtin_amdgcn_sched_barrier(0);
#pragma unroll
        for (int ks=0; ks<2; ++ks){
            bf16x8 af[MR], bv[NR];
            const int ch = (((ks*4+fq) ^ (fr&7))<<3);
#pragma unroll
            for (int j=0;j<MR;++j)
                af[j] = *(const bf16x8*)&bufA[(wm*(MR*16) + j*16 + fr)*64 + ch];
#pragma unroll
            for (int j=0;j<NR;++j)
                bv[j] = *(const bf16x8*)&bufB[(wn*(NR*16) + j*16 + fr)*64 + ch];
            __builtin_amdgcn_s_setprio(1);
#pragma unroll
            for (int mi=0;mi<MR;++mi)
#pragma unroll
            for (int ni=0;ni<NR;++ni)
                acc[mi][ni] = __builtin_amdgcn_mfma_f32_16x16x32_bf16(
                    af[mi], bv[ni], acc[mi][ni], 0,0,0);
            __builtin_amdgcn_s_setprio(0);
        }
        asm volatile("s_waitcnt lgkmcnt(0)" ::: "memory");
        __builtin_amdgcn_s_barrier();
        if (t+2<nt) STAGE(t+2, t&1);
    }

    float thr = 0.f;
    if constexpr (EPI==EPI_ADJ || EPI==EPI_DEG) thr = scal[sidx];

    if constexpr (EPI==EPI_DEG){
        float* deg = (float*)Cout;
#pragma unroll
        for (int mi=0;mi<MR;++mi){
#pragma unroll
            for (int r=0;r<4;++r){
                float s = 0.f;
#pragma unroll
                for (int ni=0;ni<NR;++ni)
                    s += sigm_f(10.f*(acc[mi][ni][r] - thr));
                s += __shfl_xor(s, 1);
                s += __shfl_xor(s, 2);
                s += __shfl_xor(s, 4);
                s += __shfl_xor(s, 8);
                if (fr == 0)
                    atomicAdd(&deg[by*BM + wm*(MR*16) + mi*16 + fq*4 + r], s);
            }
        }
        return;
    }

#pragma unroll
    for (int mi=0;mi<MR;++mi){
#pragma unroll
        for (int ni=0;ni<NR;++ni){
            const int col = bx*BN + wn*(NR*16) + ni*16 + fr;
#pragma unroll
            for (int r=0;r<4;++r){
                const int row = by*BM + wm*(MR*16) + mi*16 + fq*4 + r;
                const float v = acc[mi][ni][r];
                const long ci = (long)row*ldc + col;
                if constexpr (EPI==EPI_ADJ)       ((bf16*)Cout)[ci] = (bf16)sigm_f(10.f*(v - thr));
                else if constexpr (EPI==EPI_BF16) ((bf16*)Cout)[ci] = (bf16)v;
                else if constexpr (EPI==EPI_GELU_BIAS) ((bf16*)Cout)[ci] = (bf16)gelu_f(v + bias[col]);
                else if constexpr (EPI==EPI_BIAS_F32)  ((float*)Cout)[ci] = v + bias[col];
                else if constexpr (EPI==EPI_F32)       ((float*)Cout)[ci] = v;
                else if constexpr (EPI==EPI_XUPD){
                    const float u = 0.2f*(v + bias[col]);
                    xu0[ci] += u;
                }
                else if constexpr (EPI==EPI_XUPDB){
                    const float u = 0.2f*(v + bias[col]);
                    const float n0 = xu0[ci] + u;
                    xu0[ci] = n0;
                    xbp[ci] = (bf16)n0;
                    xbp[ci + (long)2048*1024] = (bf16)(n0 + xu1[ci]);  // x1 = x0 + delta
                }
                else if constexpr (EPI==EPI_XUPDT){
                    const float u = 0.2f*(v + bias[col]);
                    const float n0 = xu0[ci] + u;
                    xu0[ci] = n0;
                    ((bf16*)Cout)[(long)row*2048 + col] = (bf16)n0;  // comb half
                    xbp[(long)col*2048 + row] = (bf16)n0;            // x0T
                }
            }
        }
    }
}

// ---------------------------------------------------------------------------
// 8-phase head GEMM (r14-verified, FROZEN): 256x256, quadrant phases, phase-
// aligned A staging units, vmcnt(6), full fencing, plain M-inner.
// ---------------------------------------------------------------------------
template<int EPI>
__global__ __launch_bounds__(512, 2)
void gemm8(const bf16* __restrict__ A, const bf16* __restrict__ B,
           int M, int N, int K, void* __restrict__ Cout, int ldc,
           const float* __restrict__ bias)
{
    __shared__ bf16 sm[65536];
    const int nbm = M>>8;
    const int wg = blockIdx.x;
    const int by = wg % nbm, bx = wg / nbm;
    const int tid = threadIdx.x, lane = tid&63, wid = tid>>6;
    const int wm = wid>>2, wn = wid&3;
    const int fr = lane&15, fq = lane>>4;

    const bf16* Ag = A + (long)(by*256 + (tid>>3))*K + (((tid&7) ^ ((tid>>3)&7))<<3);
    const bf16* Bg = B + (long)(bx*256 + (tid>>3))*K + (((tid&7) ^ ((tid>>3)&7))<<3);

    auto SA = [&](int tt, int h){
        bf16* d = sm + (tt&1)*32768 + wid*512;
        const long ko = (long)tt*64;
        gload16(Ag + (long)(h*64)*K + ko,       d + h*4096);
        gload16(Ag + (long)(128+h*64)*K + ko,   d + 8192 + h*4096);
    };
    auto SB = [&](int tt, int h){
        bf16* d = sm + (tt&1)*32768 + 16384 + wid*512;
        const long ko = (long)tt*64;
#pragma unroll
        for (int g=0; g<2; ++g)
            gload16(Bg + (long)(h*2+g)*64*K + ko, d + (h*2+g)*4096);
    };

    f32x4 acc[8][4] = {};
    bf16x8 aCur[8], b0[4], b1[4];
    const int nt = K >> 6;

    SA(0,0); SB(0,0); SA(0,1); SB(0,1);
    SA(1,0); SB(1,0); SA(1,1);
    SCHED_FENCE();

    for (int t=0; t<nt; ++t){
        const bf16* bufA = sm + (t&1)*32768;
        const bf16* bufB = bufA + 16384;

        auto LDA = [&](int mh){
#pragma unroll
            for (int ks=0;ks<2;++ks){
                const int ch = (((ks*4+fq) ^ (fr&7))<<3);
#pragma unroll
                for (int j=0;j<4;++j)
                    aCur[ks*4+j] = *(const bf16x8*)&bufA[(wm*128 + mh*64 + j*16 + fr)*64 + ch];
            }
        };
        auto LDB = [&](int nh, bf16x8* dst){
#pragma unroll
            for (int ks=0;ks<2;++ks){
                const int ch = (((ks*4+fq) ^ (fr&7))<<3);
#pragma unroll
                for (int j=0;j<2;++j)
                    dst[ks*2+j] = *(const bf16x8*)&bufB[(wn*64 + nh*32 + j*16 + fr)*64 + ch];
            }
        };
        auto QMFMA = [&](int mh, int nh, bf16x8* bArr){
            __builtin_amdgcn_s_setprio(1);
#pragma unroll
            for (int ks=0;ks<2;++ks)
#pragma unroll
            for (int j=0;j<4;++j)
#pragma unroll
            for (int jj=0;jj<2;++jj)
                acc[mh*4+j][nh*2+jj] = __builtin_amdgcn_mfma_f32_16x16x32_bf16(
                    aCur[ks*4+j], bArr[ks*2+jj], acc[mh*4+j][nh*2+jj], 0,0,0);
            __builtin_amdgcn_s_setprio(0);
            SCHED_FENCE();
        };

        // ---- phase 1: Q(0,0) ----
        if (t+1<nt) asm volatile("s_waitcnt vmcnt(6)" ::: "memory");
        else        asm volatile("s_waitcnt vmcnt(0)" ::: "memory");
        __builtin_amdgcn_s_barrier();
        SCHED_FENCE();
        if (t+1<nt) SB(t+1,1);
        SCHED_FENCE();
        LDA(0); LDB(0, b0);
        asm volatile("s_waitcnt lgkmcnt(0)" ::: "memory");
        SCHED_FENCE();
        QMFMA(0,0,b0);
        // ---- phase 2: Q(0,1) ----
        __builtin_amdgcn_s_barrier();
        SCHED_FENCE();
        if (t+2<nt) SA(t+2,0);
        SCHED_FENCE();
        LDB(1, b1);
        asm volatile("s_waitcnt lgkmcnt(0)" ::: "memory");
        SCHED_FENCE();
        QMFMA(0,1,b1);
        // ---- phase 3: Q(1,1) ----
        __builtin_amdgcn_s_barrier();
        SCHED_FENCE();
        if (t+2<nt) SB(t+2,0);
        SCHED_FENCE();
        LDA(1);
        asm volatile("s_waitcnt lgkmcnt(0)" ::: "memory");
        SCHED_FENCE();
        QMFMA(1,1,b1);
        // ---- phase 4: Q(1,0) ----
        __builtin_amdgcn_s_barrier();
        SCHED_FENCE();
        if (t+2<nt) SA(t+2,1);
        SCHED_FENCE();
        QMFMA(1,0,b0);
    }

#pragma unroll
    for (int mi=0;mi<8;++mi){
#pragma unroll
        for (int ni=0;ni<4;++ni){
            const int col = bx*256 + wn*64 + ni*16 + fr;
#pragma unroll
            for (int r=0;r<4;++r){
                const int row = by*256 + wm*128 + mi*16 + fq*4 + r;
                const float v = acc[mi][ni][r];
                const long ci = (long)row*ldc + col;
                if constexpr (EPI==EPI_F32)            ((float*)Cout)[ci] = v;
                else if constexpr (EPI==EPI_BIAS_F32)  ((float*)Cout)[ci] = v + bias[col];
                else                                   ((bf16*)Cout)[ci] = (bf16)v;
            }
        }
    }
}

// ---------------------------------------------------------------------------
// small kernels
// ---------------------------------------------------------------------------
__global__ void prep_kernel(const float* __restrict__ cs,
                            const float* __restrict__ W1, const float* __restrict__ b1,
                            const float* __restrict__ W2, const float* __restrict__ b2,
                            float* __restrict__ thrs)
{
    __shared__ float cp[1024];
    __shared__ float part[8][32];
    __shared__ float h[32];
    const int tid = threadIdx.x;
    for (int j = tid; j < 1024; j += 256){
        float s = 0.f;
#pragma unroll
        for (int r = 0; r < 8; r++) s += cs[r*1024 + j];
        cp[j] = s * 0.125f;
    }
    __syncthreads();
    const int t = tid & 31, g = tid >> 5;
    float p = 0.f;
    for (int j = g*128; j < g*128+128; j++) p += cp[j] * W1[j*32 + t];
    part[g][t] = p;
    __syncthreads();
    if (tid < 32){
        float s = b1[tid];
#pragma unroll
        for (int q=0;q<8;q++) s += part[q][tid];
        h[tid] = gelu_f(s);
    }
    __syncthreads();
    if (tid < 4){
        float z = b2[tid];
        for (int k=0;k<32;k++) z += h[k]*W2[k*4 + tid];
        thrs[tid] = sigm_f(z);
    }
    if (tid == 4) thrs[4] = 0.5f;   // betti threshold
}

// batch 0: x0 = embed[tok0] + pos.  batch-1 slot: DELTA = embed[tok1] - embed[tok0]
// (pos cancels; levels only update x0, x1 is reconstructed at the end).
__global__ void embed_kernel(const int* __restrict__ tok, const float* __restrict__ emb,
                             const float* __restrict__ pos, float* __restrict__ x)
{
    const long i = (long)blockIdx.x*256 + threadIdx.x;
    const int  d4 = i & 255;
    const long bt = i >> 8;
    const int  t  = (int)(bt & 2047);
    f32x4 e1 = *(const f32x4*)(emb + (long)tok[bt]*1024 + d4*4);
    if (bt < 2048){
        f32x4 p = *(const f32x4*)(pos + (long)t*1024 + d4*4);
        *(f32x4*)(x + i*4) = e1 + p;
    } else {
        f32x4 e0 = *(const f32x4*)(emb + (long)tok[t]*1024 + d4*4);
        *(f32x4*)(x + i*4) = e1 - e0;
    }
}

// batched f32->bf16 transpose: nb slices of [R][C] -> [C][R]
__global__ void transpose_f2b(const float* __restrict__ in, int ldin, long istr,
                              bf16* __restrict__ out, int ldout, long ostr,
                              int R, int C)
{
    __shared__ float tile[32][33];
    const int nbx = C >> 5, nby = R >> 5;
    const int per = nbx*nby;
    const int l  = blockIdx.x / per;
    const int rm = blockIdx.x % per;
    const int bx = rm % nbx, by = rm / nbx;
    const float* inl = in + (long)l*istr;
    bf16* outl = out + (long)l*ostr;
    const int tx = threadIdx.x & 31, ty = threadIdx.x >> 5;
#pragma unroll
    for (int i=0;i<32;i+=8)
        tile[ty+i][tx] = inl[(long)(by*32+ty+i)*ldin + bx*32+tx];
    __syncthreads();
#pragma unroll
    for (int i=0;i<32;i+=8)
        outl[(long)(bx*32+ty+i)*ldout + by*32+tx] = (bf16)tile[tx][ty+i];
}

__global__ void rownorm_kernel(const float* __restrict__ x, bf16* __restrict__ xn,
                               bf16* __restrict__ x0b, int ld0)
{
    const long t = blockIdx.x; const int tid = threadIdx.x;
    f32x4 v = *(const f32x4*)(x + t*1024 + tid*4);
    float s = v.x*v.x + v.y*v.y + v.z*v.z + v.w*v.w;
#pragma unroll
    for (int o=32;o>0;o>>=1) s += __shfl_down(s, o);
    __shared__ float red[4];
    if ((tid&63)==0) red[tid>>6] = s;
    __syncthreads();
    const float tot = red[0]+red[1]+red[2]+red[3];
    const float inv = 1.0f / fmaxf(sqrtf(tot), 1e-12f);
    bf16x4 a;
    a[0]=(bf16)(v.x*inv); a[1]=(bf16)(v.y*inv); a[2]=(bf16)(v.z*inv); a[3]=(bf16)(v.w*inv);
    *(bf16x4*)(xn + t*1024 + tid*4) = a;
    if (x0b){
        bf16x4 b;
        b[0]=(bf16)v.x; b[1]=(bf16)v.y; b[2]=(bf16)v.z; b[3]=(bf16)v.w;
        *(bf16x4*)(x0b + t*ld0 + tid*4) = b;
    }
}

__global__ void zero_kernel(float* __restrict__ p)
{
    p[blockIdx.x*256 + threadIdx.x] = 0.f;
}

__global__ void betti_kernel(const float* __restrict__ deg, float* __restrict__ betti)
{
    const int tid = threadIdx.x;
    float s = 0.f, c = 0.f;
#pragma unroll
    for (int i=0;i<8;i++){
        const float d = deg[tid*8 + i];
        s += d;  c += (d < 0.5f) ? 1.f : 0.f;
    }
#pragma unroll
    for (int o=32;o>0;o>>=1){ s += __shfl_down(s,o); c += __shfl_down(c,o); }
    __shared__ float ss[4], cc[4];
    if ((tid&63)==0){ ss[tid>>6]=s; cc[tid>>6]=c; }
    __syncthreads();
    if (tid==0){
        const float S = ss[0]+ss[1]+ss[2]+ss[3];
        const float C = cc[0]+cc[1]+cc[2]+cc[3];
        const float ne = 0.5f*S;
        const float b1 = ne - 2048.f + C + 1.f;
        betti[0] = C;
        betti[1] = b1 > 0.f ? b1 : 0.f;
    }
}

__global__ void b1eff_kernel(const float* __restrict__ ib1, const float* __restrict__ iW1,
                             const float* __restrict__ betti, float* __restrict__ out)
{
    const int j = blockIdx.x*256 + threadIdx.x;
    out[j] = ib1[j] + betti[0]*iW1[(long)1024*2048 + j] + betti[1]*iW1[(long)1025*2048 + j];
}

__global__ void ln_kernel(const float* __restrict__ y, const float* __restrict__ g,
                          const float* __restrict__ b, bf16* __restrict__ out)
{
    const long t = blockIdx.x; const int tid = threadIdx.x;
    f32x4 v = *(const f32x4*)(y + t*1024 + tid*4);
    float s  = v.x+v.y+v.z+v.w;
    float s2 = v.x*v.x+v.y*v.y+v.z*v.z+v.w*v.w;
#pragma unroll
    for (int o=32;o>0;o>>=1){ s += __shfl_down(s,o); s2 += __shfl_down(s2,o); }
    __shared__ float ss[4], qq[4];
    if ((tid&63)==0){ ss[tid>>6]=s; qq[tid>>6]=s2; }
    __syncthreads();
    const float S = ss[0]+ss[1]+ss[2]+ss[3], Q = qq[0]+qq[1]+qq[2]+qq[3];
    const float mu  = S * (1.f/1024.f);
    const float var = Q * (1.f/1024.f) - mu*mu;
    const float inv = rsqrtf(var + 1e-5f);
    f32x4 gv = *(const f32x4*)(g + tid*4);
    f32x4 bv = *(const f32x4*)(b + tid*4);
    bf16x4 o;
    o[0] = (bf16)((v.x - mu)*inv*gv.x + bv.x);
    o[1] = (bf16)((v.y - mu)*inv*gv.y + bv.y);
    o[2] = (bf16)((v.z - mu)*inv*gv.z + bv.z);
    o[3] = (bf16)((v.w - mu)*inv*gv.w + bv.w);
    *(bf16x4*)(out + t*1024 + tid*4) = o;
}

// ---------------------------------------------------------------------------
extern "C" void kernel_launch(void* const* d_in, const int* in_sizes, int n_in,
                              void* d_out, int out_size, void* d_ws, size_t ws_size,
                              hipStream_t stream)
{
    const int*   tokens = (const int*)  d_in[0];
    const float* cstate = (const float*)d_in[1];
    const float* embedW = (const float*)d_in[2];
    const float* posW   = (const float*)d_in[3];
    const float* thrW1  = (const float*)d_in[8];
    const float* thrb1  = (const float*)d_in[9];
    const float* thrW2  = (const float*)d_in[10];
    const float* thrb2  = (const float*)d_in[11];
    const float* simpW1 = (const float*)d_in[12];
    const float* simpb1 = (const float*)d_in[13];
    const float* simpW2 = (const float*)d_in[14];
    const float* simpb2 = (const float*)d_in[15];
    const float* intW1  = (const float*)d_in[16];
    const float* intb1  = (const float*)d_in[17];
    const float* intW2  = (const float*)d_in[18];
    const float* intb2  = (const float*)d_in[19];
    const float* lng    = (const float*)d_in[20];
    const float* lnb    = (const float*)d_in[21];
    const float* headW  = (const float*)d_in[22];
    float* out = (float*)d_out;

    size_t off = 0;
    auto carve = [&](size_t bytes) -> void* {
        void* p = (char*)d_ws + off;
        off += (bytes + 255) & ~(size_t)255;
        return p;
    };
    float* x_f32   = (float*)carve(16777216);   // [0]=x0 (updated), [1]=delta (const)
    bf16*  xn      = (bf16*) carve(4194304);
    bf16*  x0T     = (bf16*) carve(4194304);
    bf16*  comb    = (bf16*) carve(8388608);
    bf16*  adj     = (bf16*) carve(8388608);
    bf16*  h1      = (bf16*) carve(4194304);
    bf16*  xb      = (bf16*) carve(8388608);
    bf16*  w1T     = (bf16*) carve(16777216);
    bf16*  w2T     = (bf16*) carve(8388608);
    bf16*  i1T     = (bf16*) carve(4194304);
    bf16*  i2T     = (bf16*) carve(4194304);
    bf16*  hT      = (bf16*) carve(65536000);
    float* degree  = (float*)carve(8192);
    float* b1eff   = (float*)carve(8192);
    float* thrs    = (float*)carve(64);
    float* betti   = (float*)carve(64);
    bf16*  h2  = comb;
    float* yv  = x_f32;
    bf16*  xln = xn;

    const dim3 blk(256);
    const dim3 blk512(512);

    prep_kernel<<<1, blk, 0, stream>>>(cstate, thrW1, thrb1, thrW2, thrb2, thrs);
    embed_kernel<<<4096, blk, 0, stream>>>(tokens, embedW, posW, x_f32);

    // weight transposes (batched): w1T x4, w2T x4, then i1T, i2T, hT
    transpose_f2b<<<4*(1024/32)*(2048/32), blk, 0, stream>>>(
        simpW1, 1024, (long)2048*1024, w1T, 2048, (long)1024*2048, 2048, 1024);
    transpose_f2b<<<4*(1024/32)*(1024/32), blk, 0, stream>>>(
        simpW2, 1024, (long)1024*1024, w2T, 1024, (long)1024*1024, 1024, 1024);
    transpose_f2b<<<(2048/32)*(1024/32), blk, 0, stream>>>(
        intW1, 2048, 0, i1T, 1024, 0, 1024, 2048);
    transpose_f2b<<<(1024/32)*(2048/32), blk, 0, stream>>>(
        intW2, 1024, 0, i2T, 2048, 0, 2048, 1024);
    transpose_f2b<<<(32000/32)*(1024/32), blk, 0, stream>>>(
        headW, 32000, 0, hT, 1024, 0, 1024, 32000);

    for (int l=0;l<4;l++){
        if (l == 0){
            rownorm_kernel<<<2048, blk, 0, stream>>>(x_f32, xn, comb, 2048);
            transpose_f2b<<<(1024/32)*(2048/32), blk, 0, stream>>>(
                x_f32, 1024, 0, x0T, 2048, 0, 2048, 1024);
        } else {
            // comb-half and x0T were written by the previous level's XUPDT
            rownorm_kernel<<<2048, blk, 0, stream>>>(x_f32, xn, nullptr, 0);
        }
        gemm_p<64,128,2,2,3,EPI_ADJ><<<32*16, blk, 0, stream>>>(
            xn, xn, 2048, 2048, 1024, adj, 2048, nullptr, thrs, l, nullptr, nullptr, nullptr);
        gemm_p<64,64,2,2,4,EPI_BF16><<<32*16, blk, 0, stream>>>(
            adj, x0T, 2048, 1024, 2048, comb + 1024, 2048, nullptr, nullptr, 0, nullptr, nullptr, nullptr);
        gemm_p<64,64,2,2,4,EPI_GELU_BIAS><<<32*16, blk, 0, stream>>>(
            comb, w1T + (long)l*1024*2048, 2048, 1024, 2048, h1, 1024,
            simpb1 + l*1024, nullptr, 0, nullptr, nullptr, nullptr);
        if (l < 3)
            gemm_p<64,64,2,2,4,EPI_XUPDT><<<32*16, blk, 0, stream>>>(
                h1, w2T + (long)l*1024*1024, 2048, 1024, 1024, comb, 1024,
                simpb2 + l*1024, nullptr, 0, x_f32, nullptr, x0T);
        else
            gemm_p<64,64,2,2,4,EPI_XUPDB><<<32*16, blk, 0, stream>>>(
                h1, w2T + (long)l*1024*1024, 2048, 1024, 1024, nullptr, 1024,
                simpb2 + l*1024, nullptr, 0, x_f32, x_f32 + (long)2048*1024, xb);
    }

    // betti pass: fused degree (no adj materialization)
    rownorm_kernel<<<2048, blk, 0, stream>>>(x_f32, xn, nullptr, 0);
    zero_kernel<<<8, blk, 0, stream>>>(degree);
    gemm_p<64,128,2,2,3,EPI_DEG><<<32*16, blk, 0, stream>>>(
        xn, xn, 2048, 2048, 1024, degree, 0, nullptr, thrs, 4, nullptr, nullptr, nullptr);
    betti_kernel<<<1, blk, 0, stream>>>(degree, betti);
    b1eff_kernel<<<8, blk, 0, stream>>>(intb1, intW1, betti, b1eff);

    gemm_p<128,128,2,2,2,EPI_GELU_BIAS><<<32*16, blk, 0, stream>>>(
        xb, i1T, 4096, 2048, 1024, h2, 2048, b1eff, nullptr, 0, nullptr, nullptr, nullptr);
    gemm_p<64,128,2,2,3,EPI_BIAS_F32><<<64*8, blk, 0, stream>>>(
        h2, i2T, 4096, 1024, 2048, yv, 1024, intb2, nullptr, 0, nullptr, nullptr, nullptr);
    ln_kernel<<<4096, blk, 0, stream>>>(yv, lng, lnb, xln);
    gemm8<EPI_F32><<<16*125, blk512, 0, stream>>>(
        xln, hT, 4096, 32000, 1024, out, 32000, nullptr);
}